// Round 1
// baseline (291.080 us; speedup 1.0000x reference)
//
#include <hip/hip_runtime.h>
#include <hip/hip_bf16.h>

typedef unsigned short u16;
typedef __attribute__((ext_vector_type(8))) short bf16x8;
typedef __attribute__((ext_vector_type(4))) float f32x4;

typedef __attribute__((address_space(1))) const void cgvoid;
typedef __attribute__((address_space(3))) void lvoid;

static __device__ __forceinline__ u16 f2bf(float x) {
    __hip_bfloat16 h = __float2bfloat16(x);
    return __builtin_bit_cast(u16, h);
}

static __device__ __forceinline__ void gload_lds16(const u16* g, u16* l) {
    __builtin_amdgcn_global_load_lds((cgvoid*)g, (lvoid*)l, 16, 0, 0);
}

// ---------------------------------------------------------------------------
// fp32 -> bf16 elementwise convert (vectorized, grid-stride)
// ---------------------------------------------------------------------------
__global__ __launch_bounds__(256) void cvt_f32_bf16(
    const float* __restrict__ in, u16* __restrict__ out, int n4)
{
    int i = blockIdx.x * blockDim.x + threadIdx.x;
    const int stride = gridDim.x * blockDim.x;
    for (; i < n4; i += stride) {
        const float4 v = ((const float4*)in)[i];
        ushort4 pk;
        pk.x = f2bf(v.x); pk.y = f2bf(v.y); pk.z = f2bf(v.z); pk.w = f2bf(v.w);
        ((ushort4*)out)[i] = pk;
    }
}

// ---------------------------------------------------------------------------
// LayerNorm over H=1024, one block (256 thr) per row, bf16 output
// ---------------------------------------------------------------------------
__global__ __launch_bounds__(256) void ln_bf16(
    const float* __restrict__ x, const float* __restrict__ gw,
    const float* __restrict__ bw, u16* __restrict__ out)
{
    const int row = blockIdx.x;
    const int t = threadIdx.x;
    const float4 v = ((const float4*)(x + (size_t)row * 1024))[t];
    float s  = v.x + v.y + v.z + v.w;
    float sq = v.x*v.x + v.y*v.y + v.z*v.z + v.w*v.w;
#pragma unroll
    for (int d = 1; d < 64; d <<= 1) {
        s  += __shfl_xor(s, d, 64);
        sq += __shfl_xor(sq, d, 64);
    }
    __shared__ float ss[4], ssq[4];
    const int wave = t >> 6, lane = t & 63;
    if (lane == 0) { ss[wave] = s; ssq[wave] = sq; }
    __syncthreads();
    s  = ss[0] + ss[1] + ss[2] + ss[3];
    sq = ssq[0] + ssq[1] + ssq[2] + ssq[3];
    const float mu = s * (1.f / 1024.f);
    const float rinv = rsqrtf(sq * (1.f / 1024.f) - mu * mu + 1e-5f);
    const float4 gv = ((const float4*)gw)[t];
    const float4 bv = ((const float4*)bw)[t];
    ushort4 pk;
    pk.x = f2bf((v.x - mu) * rinv * gv.x + bv.x);
    pk.y = f2bf((v.y - mu) * rinv * gv.y + bv.y);
    pk.z = f2bf((v.z - mu) * rinv * gv.z + bv.z);
    pk.w = f2bf((v.w - mu) * rinv * gv.w + bv.w);
    ((ushort4*)(out + (size_t)row * 1024))[t] = pk;
}

// ---------------------------------------------------------------------------
// C[M][N] = A[M][K] @ W[N][K]^T + bias (+ epilogue)
// 128x128 tile, BK=64, 4 waves, 4x4 16x16x32 bf16 MFMA per wave
// EPI: 0 = bf16 out, 1 = f32 out + residual, 2 = bf16 out with bloom-gelu
// ---------------------------------------------------------------------------
template<int EPI>
__global__ __launch_bounds__(256) void gemm_bt(
    const u16* __restrict__ A, const u16* __restrict__ Bw,
    const float* __restrict__ bias, const float* __restrict__ res,
    void* __restrict__ Cout, int M, int N, int K)
{
    __shared__ __align__(16) u16 As[128 * 64];
    __shared__ __align__(16) u16 Bs[128 * 64];
    const int t = threadIdx.x;
    const int lane = t & 63;
    const int wave = t >> 6;
    const int wr = wave >> 1, wc = wave & 1;
    const int g = lane >> 4, r16 = lane & 15;
    const int tile_m = blockIdx.x * 128;
    const int tile_n = blockIdx.y * 128;

    f32x4 acc[4][4] = {};

    for (int k0 = 0; k0 < K; k0 += 64) {
        __syncthreads();
#pragma unroll
        for (int i = 0; i < 4; ++i) {
            const int off = (t + i * 256) * 8;   // element offset in 128x64 tile
            const int row = off >> 6;
            const int col = off & 63;
            gload_lds16(A  + (size_t)(tile_m + row) * K + k0 + col, As + off);
            gload_lds16(Bw + (size_t)(tile_n + row) * K + k0 + col, Bs + off);
        }
        __syncthreads();

        bf16x8 af[4][2], bfr[4][2];
#pragma unroll
        for (int mi = 0; mi < 4; ++mi)
#pragma unroll
            for (int ks = 0; ks < 2; ++ks)
                af[mi][ks] = *(const bf16x8*)(As + (wr*64 + mi*16 + r16)*64 + ks*32 + g*8);
#pragma unroll
        for (int ni = 0; ni < 4; ++ni)
#pragma unroll
            for (int ks = 0; ks < 2; ++ks)
                bfr[ni][ks] = *(const bf16x8*)(Bs + (wc*64 + ni*16 + r16)*64 + ks*32 + g*8);
#pragma unroll
        for (int mi = 0; mi < 4; ++mi)
#pragma unroll
            for (int ni = 0; ni < 4; ++ni) {
                acc[mi][ni] = __builtin_amdgcn_mfma_f32_16x16x32_bf16(af[mi][0], bfr[ni][0], acc[mi][ni], 0, 0, 0);
                acc[mi][ni] = __builtin_amdgcn_mfma_f32_16x16x32_bf16(af[mi][1], bfr[ni][1], acc[mi][ni], 0, 0, 0);
            }
    }

#pragma unroll
    for (int mi = 0; mi < 4; ++mi) {
#pragma unroll
        for (int ni = 0; ni < 4; ++ni) {
            const int col = tile_n + wc*64 + ni*16 + r16;
            const float bv = bias[col];
#pragma unroll
            for (int r = 0; r < 4; ++r) {
                const int row = tile_m + wr*64 + mi*16 + g*4 + r;
                const float v = acc[mi][ni][r] + bv;
                if constexpr (EPI == 0) {
                    ((u16*)Cout)[(size_t)row * N + col] = f2bf(v);
                } else if constexpr (EPI == 1) {
                    ((float*)Cout)[(size_t)row * N + col] = v + res[(size_t)row * N + col];
                } else {
                    const float c = 0.79788456f * v * (1.0f + 0.044715f * v * v);
                    ((u16*)Cout)[(size_t)row * N + col] = f2bf(0.5f * v * (1.0f + tanhf(c)));
                }
            }
        }
    }
}

// ---------------------------------------------------------------------------
// Flash-style causal attention with alibi.
// fused: bf16 [S][NH*192] (q|k|v per head). grid = (S/64, NH), 256 threads.
// Each wave owns 16 q-rows; K/V tiles of 64 keys staged in LDS (V transposed).
// ctx out: bf16 [S][1024]
// ---------------------------------------------------------------------------
__global__ __launch_bounds__(256) void attn_fused(
    const u16* __restrict__ fused, const float* __restrict__ alibi,
    u16* __restrict__ ctx)
{
    const int q0 = blockIdx.x * 64;
    const int h = blockIdx.y;
    const int t = threadIdx.x;
    const int lane = t & 63, wave = t >> 6;
    const int g = lane >> 4, r16 = lane & 15;
    const int qw0 = q0 + wave * 16;

    __shared__ __align__(16) u16 Ks[64 * 64];
    __shared__ __align__(16) u16 Vt[64 * 64];
    __shared__ __align__(16) u16 Ps[4 * 16 * 64];
    u16* Pw = Ps + wave * (16 * 64);

    bf16x8 qf[2];
#pragma unroll
    for (int ks = 0; ks < 2; ++ks)
        qf[ks] = *(const bf16x8*)(fused + (size_t)(qw0 + r16) * 3072 + h*192 + ks*32 + g*8);

    f32x4 o_acc[4] = {};
    float m_r[4], l_r[4];
#pragma unroll
    for (int r = 0; r < 4; ++r) { m_r[r] = -3.0e38f; l_r[r] = 0.f; }

    const int nkt = blockIdx.x + 1;
    for (int kt = 0; kt < nkt; ++kt) {
        const int kt0 = kt * 64;
        __syncthreads();
        // stage K tile (64x64) linear via global_load_lds
#pragma unroll
        for (int i = 0; i < 2; ++i) {
            const int off = (t + i * 256) * 8;
            const int tok = off >> 6, d = off & 63;
            gload_lds16(fused + (size_t)(kt0 + tok) * 3072 + h*192 + 64 + d, Ks + off);
        }
        // stage V transposed: Vt[d][tok]
        {
            const int tok = t >> 2, d0 = (t & 3) * 16;
            const u16* src = fused + (size_t)(kt0 + tok) * 3072 + h*192 + 128 + d0;
            union { bf16x8 v; u16 e[8]; } u0, u1;
            u0.v = *(const bf16x8*)src;
            u1.v = *(const bf16x8*)(src + 8);
#pragma unroll
            for (int e = 0; e < 8; ++e) {
                Vt[(d0 + e) * 64 + tok]     = u0.e[e];
                Vt[(d0 + 8 + e) * 64 + tok] = u1.e[e];
            }
        }
        __syncthreads();

        if (kt0 <= qw0 + 15) {   // wave-uniform: this wave has rows >= kt0
            // QK^T: scores 16 q-rows x 64 keys
            f32x4 sc[4] = {};
#pragma unroll
            for (int kn = 0; kn < 4; ++kn) {
#pragma unroll
                for (int ks = 0; ks < 2; ++ks) {
                    const bf16x8 kf = *(const bf16x8*)(Ks + (kn*16 + r16)*64 + ks*32 + g*8);
                    sc[kn] = __builtin_amdgcn_mfma_f32_16x16x32_bf16(qf[ks], kf, sc[kn], 0, 0, 0);
                }
            }
            // scale + alibi + causal mask; per-row max
            float sv[4][4];
            float rowmax[4] = {-3.0e38f, -3.0e38f, -3.0e38f, -3.0e38f};
#pragma unroll
            for (int kn = 0; kn < 4; ++kn) {
                const int key = kt0 + kn*16 + r16;
                const float al = alibi[(size_t)h * 2048 + key];
#pragma unroll
                for (int r = 0; r < 4; ++r) {
                    const int qrow = qw0 + g*4 + r;
                    float s = sc[kn][r] * 0.125f + al;
                    s = (key <= qrow) ? s : -3.0e38f;
                    sv[kn][r] = s;
                    rowmax[r] = fmaxf(rowmax[r], s);
                }
            }
#pragma unroll
            for (int r = 0; r < 4; ++r) {
#pragma unroll
                for (int d = 1; d < 16; d <<= 1)
                    rowmax[r] = fmaxf(rowmax[r], __shfl_xor(rowmax[r], d, 64));
            }
            float scale[4], psum[4];
#pragma unroll
            for (int r = 0; r < 4; ++r) {
                const float mnew = fmaxf(m_r[r], rowmax[r]);
                scale[r] = __expf(m_r[r] - mnew);
                m_r[r] = mnew;
                psum[r] = 0.f;
            }
            // P = exp(s - m), write to per-wave LDS (transpose for PV A-frag)
#pragma unroll
            for (int kn = 0; kn < 4; ++kn) {
#pragma unroll
                for (int r = 0; r < 4; ++r) {
                    const float p = __expf(sv[kn][r] - m_r[r]);
                    psum[r] += p;
                    Pw[(g*4 + r) * 64 + kn*16 + r16] = f2bf(p);
                }
            }
#pragma unroll
            for (int r = 0; r < 4; ++r) {
#pragma unroll
                for (int d = 1; d < 16; d <<= 1)
                    psum[r] += __shfl_xor(psum[r], d, 64);
                l_r[r] = l_r[r] * scale[r] + psum[r];
            }
#pragma unroll
            for (int nd = 0; nd < 4; ++nd)
#pragma unroll
                for (int r = 0; r < 4; ++r)
                    o_acc[nd][r] *= scale[r];

            // per-wave LDS fence: P writes visible to all lanes of this wave
            asm volatile("s_waitcnt lgkmcnt(0)" ::: "memory");

            bf16x8 pf[2];
            pf[0] = *(const bf16x8*)(Pw + r16*64 + g*8);
            pf[1] = *(const bf16x8*)(Pw + r16*64 + 32 + g*8);
#pragma unroll
            for (int nd = 0; nd < 4; ++nd) {
#pragma unroll
                for (int ks = 0; ks < 2; ++ks) {
                    const bf16x8 vf = *(const bf16x8*)(Vt + (nd*16 + r16)*64 + ks*32 + g*8);
                    o_acc[nd] = __builtin_amdgcn_mfma_f32_16x16x32_bf16(pf[ks], vf, o_acc[nd], 0, 0, 0);
                }
            }
        }
    }

#pragma unroll
    for (int nd = 0; nd < 4; ++nd) {
#pragma unroll
        for (int r = 0; r < 4; ++r) {
            const int qrow = qw0 + g*4 + r;
            const float inv = 1.0f / l_r[r];
            ctx[(size_t)qrow * 1024 + h*64 + nd*16 + r16] = f2bf(o_acc[nd][r] * inv);
        }
    }
}

// ---------------------------------------------------------------------------
extern "C" void kernel_launch(void* const* d_in, const int* in_sizes, int n_in,
                              void* d_out, int out_size, void* d_ws, size_t ws_size,
                              hipStream_t stream)
{
    (void)in_sizes; (void)n_in; (void)out_size; (void)ws_size;
    const float* hidden  = (const float*)d_in[0];
    const float* alibi   = (const float*)d_in[2];
    const float* ln1_g   = (const float*)d_in[3];
    const float* ln1_b   = (const float*)d_in[4];
    const float* qkv_w   = (const float*)d_in[5];
    const float* qkv_b   = (const float*)d_in[6];
    const float* dense_w = (const float*)d_in[7];
    const float* dense_b = (const float*)d_in[8];
    const float* ln2_g   = (const float*)d_in[9];
    const float* ln2_b   = (const float*)d_in[10];
    const float* fc1_w   = (const float*)d_in[11];
    const float* fc1_b   = (const float*)d_in[12];
    const float* fc2_w   = (const float*)d_in[13];
    const float* fc2_b   = (const float*)d_in[14];
    float* out = (float*)d_out;

    char* p = (char*)d_ws;
    u16* ln_buf   = (u16*)p;  p += (size_t)2048 * 1024 * 2;  // ln1_out, reused for ln2_out
    u16* qkv_wb   = (u16*)p;  p += (size_t)3072 * 1024 * 2;
    u16* fusedq   = (u16*)p;  p += (size_t)2048 * 3072 * 2;  // also start of hbuf alias
    u16* ctx      = (u16*)p;  p += (size_t)2048 * 1024 * 2;
    u16* dense_wb = (u16*)p;  p += (size_t)1024 * 1024 * 2;
    float* attn_o = (float*)p; p += (size_t)2048 * 1024 * 4;
    u16* fc1_wb   = (u16*)p;  p += (size_t)4096 * 1024 * 2;
    u16* fc2_wb   = (u16*)p;  p += (size_t)1024 * 4096 * 2;
    u16* hbuf = fusedq;   // 16 MB alias: fusedq+ctx dead by the time FC1 writes h

    // weight converts
    cvt_f32_bf16<<<2048, 256, 0, stream>>>(qkv_w,   qkv_wb,   3072*1024/4);
    cvt_f32_bf16<<<1024, 256, 0, stream>>>(dense_w, dense_wb, 1024*1024/4);
    cvt_f32_bf16<<<2048, 256, 0, stream>>>(fc1_w,   fc1_wb,   4096*1024/4);
    cvt_f32_bf16<<<2048, 256, 0, stream>>>(fc2_w,   fc2_wb,   1024*4096/4);

    // LN1
    ln_bf16<<<2048, 256, 0, stream>>>(hidden, ln1_g, ln1_b, ln_buf);
    // QKV: [2048,1024] @ [3072,1024]^T -> bf16 fused
    gemm_bt<0><<<dim3(16, 24), 256, 0, stream>>>(ln_buf, qkv_wb, qkv_b, nullptr, fusedq, 2048, 3072, 1024);
    // attention
    attn_fused<<<dim3(32, 16), 256, 0, stream>>>(fusedq, alibi, ctx);
    // dense + residual(hidden) -> f32 attn_o
    gemm_bt<1><<<dim3(16, 8), 256, 0, stream>>>(ctx, dense_wb, dense_b, hidden, attn_o, 2048, 1024, 1024);
    // LN2
    ln_bf16<<<2048, 256, 0, stream>>>(attn_o, ln2_g, ln2_b, ln_buf);
    // FC1 + gelu -> bf16 h
    gemm_bt<2><<<dim3(16, 32), 256, 0, stream>>>(ln_buf, fc1_wb, fc1_b, nullptr, hbuf, 2048, 4096, 1024);
    // FC2 + residual(attn_o) -> f32 out
    gemm_bt<1><<<dim3(16, 8), 256, 0, stream>>>(hbuf, fc2_wb, fc2_b, attn_o, out, 2048, 1024, 4096);
}

// Round 2
// 248.474 us; speedup vs baseline: 1.1715x; 1.1715x over previous
//
#include <hip/hip_runtime.h>
#include <hip/hip_bf16.h>

typedef unsigned short u16;
typedef __attribute__((ext_vector_type(8))) short bf16x8;
typedef __attribute__((ext_vector_type(4))) float f32x4;

typedef __attribute__((address_space(1))) const void cgvoid;
typedef __attribute__((address_space(3))) void lvoid;

static __device__ __forceinline__ u16 f2bf(float x) {
    __hip_bfloat16 h = __float2bfloat16(x);
    return __builtin_bit_cast(u16, h);
}

static __device__ __forceinline__ void gload_lds16(const u16* g, u16* l) {
    __builtin_amdgcn_global_load_lds((cgvoid*)g, (lvoid*)l, 16, 0, 0);
}

// ---------------------------------------------------------------------------
// fp32 -> bf16 elementwise convert
// ---------------------------------------------------------------------------
__global__ __launch_bounds__(256) void cvt_f32_bf16(
    const float* __restrict__ in, u16* __restrict__ out, int n4)
{
    int i = blockIdx.x * blockDim.x + threadIdx.x;
    const int stride = gridDim.x * blockDim.x;
    for (; i < n4; i += stride) {
        const float4 v = ((const float4*)in)[i];
        ushort4 pk;
        pk.x = f2bf(v.x); pk.y = f2bf(v.y); pk.z = f2bf(v.z); pk.w = f2bf(v.w);
        ((ushort4*)out)[i] = pk;
    }
}

// ---------------------------------------------------------------------------
// LayerNorm over H=1024, one block per row, bf16 out
// ---------------------------------------------------------------------------
__global__ __launch_bounds__(256) void ln_bf16(
    const float* __restrict__ x, const float* __restrict__ gw,
    const float* __restrict__ bw, u16* __restrict__ out)
{
    const int row = blockIdx.x;
    const int t = threadIdx.x;
    const float4 v = ((const float4*)(x + (size_t)row * 1024))[t];
    float s  = v.x + v.y + v.z + v.w;
    float sq = v.x*v.x + v.y*v.y + v.z*v.z + v.w*v.w;
#pragma unroll
    for (int d = 1; d < 64; d <<= 1) {
        s  += __shfl_xor(s, d, 64);
        sq += __shfl_xor(sq, d, 64);
    }
    __shared__ float ss[4], ssq[4];
    const int wave = t >> 6, lane = t & 63;
    if (lane == 0) { ss[wave] = s; ssq[wave] = sq; }
    __syncthreads();
    s  = ss[0] + ss[1] + ss[2] + ss[3];
    sq = ssq[0] + ssq[1] + ssq[2] + ssq[3];
    const float mu = s * (1.f / 1024.f);
    const float rinv = rsqrtf(sq * (1.f / 1024.f) - mu * mu + 1e-5f);
    const float4 gv = ((const float4*)gw)[t];
    const float4 bv = ((const float4*)bw)[t];
    ushort4 pk;
    pk.x = f2bf((v.x - mu) * rinv * gv.x + bv.x);
    pk.y = f2bf((v.y - mu) * rinv * gv.y + bv.y);
    pk.z = f2bf((v.z - mu) * rinv * gv.z + bv.z);
    pk.w = f2bf((v.w - mu) * rinv * gv.w + bv.w);
    ((ushort4*)(out + (size_t)row * 1024))[t] = pk;
}

// ---------------------------------------------------------------------------
// C[M][N] = A[M][K] @ W[N][K]^T + bias (+ epilogue)
// BM=128, BN in {64,128}, BK=64, 4 waves.
// EPI: 0 = bf16 out, 1 = f32 out + residual, 2 = bf16 out + bloom-gelu,
//      3 = bf16 out + transposed copy of V columns (QKV epilogue)
// ---------------------------------------------------------------------------
template<int EPI, int BN>
__global__ __launch_bounds__(256) void gemm_bt(
    const u16* __restrict__ A, const u16* __restrict__ Bw,
    const float* __restrict__ bias, const float* __restrict__ res,
    void* __restrict__ Cout, u16* __restrict__ vTout, int M, int N, int K)
{
    constexpr int WC = BN / 64;          // waves along N: 2 or 1
    constexpr int MI = (BN == 128) ? 4 : 2;
    constexpr int NI = 4;
    __shared__ __align__(16) u16 As[128 * 64];
    __shared__ __align__(16) u16 Bs[BN * 64];
    const int t = threadIdx.x;
    const int lane = t & 63;
    const int wave = t >> 6;
    const int wr = wave / WC, wc = wave % WC;
    const int g = lane >> 4, r16 = lane & 15;
    const int tile_m = blockIdx.x * 128;
    const int tile_n = blockIdx.y * BN;

    f32x4 acc[MI][NI] = {};

    for (int k0 = 0; k0 < K; k0 += 64) {
        __syncthreads();
#pragma unroll
        for (int i = 0; i < 4; ++i) {
            const int off = (t + i * 256) * 8;
            const int row = off >> 6;
            const int col = off & 63;
            gload_lds16(A + (size_t)(tile_m + row) * K + k0 + col, As + off);
        }
#pragma unroll
        for (int i = 0; i < BN / 32; ++i) {
            const int off = (t + i * 256) * 8;
            const int row = off >> 6;
            const int col = off & 63;
            gload_lds16(Bw + (size_t)(tile_n + row) * K + k0 + col, Bs + off);
        }
        __syncthreads();

        bf16x8 af[MI][2], bfr[NI][2];
#pragma unroll
        for (int mi = 0; mi < MI; ++mi)
#pragma unroll
            for (int ks = 0; ks < 2; ++ks)
                af[mi][ks] = *(const bf16x8*)(As + (wr*(MI*16) + mi*16 + r16)*64 + ks*32 + g*8);
#pragma unroll
        for (int ni = 0; ni < NI; ++ni)
#pragma unroll
            for (int ks = 0; ks < 2; ++ks)
                bfr[ni][ks] = *(const bf16x8*)(Bs + (wc*64 + ni*16 + r16)*64 + ks*32 + g*8);
#pragma unroll
        for (int mi = 0; mi < MI; ++mi)
#pragma unroll
            for (int ni = 0; ni < NI; ++ni) {
                acc[mi][ni] = __builtin_amdgcn_mfma_f32_16x16x32_bf16(af[mi][0], bfr[ni][0], acc[mi][ni], 0, 0, 0);
                acc[mi][ni] = __builtin_amdgcn_mfma_f32_16x16x32_bf16(af[mi][1], bfr[ni][1], acc[mi][ni], 0, 0, 0);
            }
    }

#pragma unroll
    for (int mi = 0; mi < MI; ++mi) {
#pragma unroll
        for (int ni = 0; ni < NI; ++ni) {
            const int col = tile_n + wc*64 + ni*16 + r16;
            const float bv = bias[col];
            const int row0 = tile_m + wr*(MI*16) + mi*16 + g*4;
            float vv[4];
#pragma unroll
            for (int r = 0; r < 4; ++r) vv[r] = acc[mi][ni][r] + bv;
#pragma unroll
            for (int r = 0; r < 4; ++r) {
                const int row = row0 + r;
                if constexpr (EPI == 0 || EPI == 3) {
                    ((u16*)Cout)[(size_t)row * N + col] = f2bf(vv[r]);
                } else if constexpr (EPI == 1) {
                    ((float*)Cout)[(size_t)row * N + col] = vv[r] + res[(size_t)row * N + col];
                } else {
                    const float x = vv[r];
                    const float c = 0.79788456f * x * (1.0f + 0.044715f * x * x);
                    // 0.5*(1+tanh(c)) == sigmoid(2c)
                    ((u16*)Cout)[(size_t)row * N + col] = f2bf(x / (1.0f + __expf(-2.0f * c)));
                }
            }
            if constexpr (EPI == 3) {
                if (((col >> 6) % 3) == 2) {     // V columns: col%192 in [128,192)
                    const int h = col / 192;
                    const int d = (col % 192) - 128;
                    ushort4 pk;
                    pk.x = f2bf(vv[0]); pk.y = f2bf(vv[1]);
                    pk.z = f2bf(vv[2]); pk.w = f2bf(vv[3]);
                    *(ushort4*)(vTout + ((size_t)(h*64 + d)) * 2048 + row0) = pk;
                }
            }
        }
    }
}

// ---------------------------------------------------------------------------
// Swapped-operand flash attention, causal + alibi. One wave (64 thr) per
// block, 16 q-rows per wave. No LDS, no barriers.
// fused: bf16 [S][NH*192] (q|k|v per head); vT: bf16 [NH][64][S].
// Lane (g,r16): q = qw0+r16 (output col), keys per acc kn:
//   key(kn,r) = kt0 + 32*(kn>>1) + 8g + 4*(kn&1) + r   (permuted K-row load)
// -> PV B-frag pf[ks] = [p[2ks][0..3], p[2ks+1][0..3]] with NO shuffle.
// ---------------------------------------------------------------------------
__global__ __launch_bounds__(64) void attn_swapped(
    const u16* __restrict__ fused, const u16* __restrict__ vT,
    const float* __restrict__ alibi, u16* __restrict__ ctx)
{
    const int bid = blockIdx.x;
    const int h = bid & 15;
    const int qt = 127 - (bid >> 4);        // heavy q-tiles dispatch first
    const int qw0 = qt * 16;
    const int lane = threadIdx.x;
    const int g = lane >> 4, r16 = lane & 15;
    const int qrow = qw0 + r16;

    const u16* qbase = fused + (size_t)qrow * 3072 + h * 192;
    bf16x8 qf[2];
    qf[0] = *(const bf16x8*)(qbase + g*8);
    qf[1] = *(const bf16x8*)(qbase + 32 + g*8);

    int prow[4];
#pragma unroll
    for (int kn = 0; kn < 4; ++kn)
        prow[kn] = 32*(kn>>1) + 8*(r16>>2) + 4*(kn&1) + (r16&3);

    f32x4 o_acc[4] = {};
    float m_r = -3.0e38f, l_r = 0.f;

    const u16* kbase = fused + h*192 + 64;
    const u16* vbase = vT + (size_t)h * 64 * 2048;
    const float* abase = alibi + (size_t)h * 2048;

    const int nkt = (qw0 >> 6) + 1;
    for (int kt = 0; kt < nkt; ++kt) {
        const int kt0 = kt * 64;

        // loads first: K frags, alibi, V frags (V latency hides under QK+softmax)
        bf16x8 kf[4][2];
#pragma unroll
        for (int kn = 0; kn < 4; ++kn) {
            const u16* kr = kbase + (size_t)(kt0 + prow[kn]) * 3072;
            kf[kn][0] = *(const bf16x8*)(kr + g*8);
            kf[kn][1] = *(const bf16x8*)(kr + 32 + g*8);
        }
        float4 al[4];
#pragma unroll
        for (int kn = 0; kn < 4; ++kn)
            al[kn] = *(const float4*)(abase + kt0 + 32*(kn>>1) + 8*g + 4*(kn&1));
        bf16x8 vf[4][2];
#pragma unroll
        for (int nd = 0; nd < 4; ++nd) {
            const u16* vr = vbase + (size_t)(nd*16 + r16) * 2048 + kt0;
            vf[nd][0] = *(const bf16x8*)(vr + g*8);
            vf[nd][1] = *(const bf16x8*)(vr + 32 + g*8);
        }

        // S^T = K @ Q^T : lane holds 16 keys for its q
        f32x4 sc[4] = {};
#pragma unroll
        for (int kn = 0; kn < 4; ++kn) {
            sc[kn] = __builtin_amdgcn_mfma_f32_16x16x32_bf16(kf[kn][0], qf[0], sc[kn], 0, 0, 0);
            sc[kn] = __builtin_amdgcn_mfma_f32_16x16x32_bf16(kf[kn][1], qf[1], sc[kn], 0, 0, 0);
        }

        // scale + alibi + causal mask, row max
        float s[4][4];
        float rmax = -3.0e38f;
#pragma unroll
        for (int kn = 0; kn < 4; ++kn) {
            const int kb = kt0 + 32*(kn>>1) + 8*g + 4*(kn&1);
            const float alv[4] = {al[kn].x, al[kn].y, al[kn].z, al[kn].w};
#pragma unroll
            for (int r = 0; r < 4; ++r) {
                float v = sc[kn][r] * 0.125f + alv[r];
                v = (kb + r <= qrow) ? v : -1.0e30f;
                s[kn][r] = v;
                rmax = fmaxf(rmax, v);
            }
        }
        rmax = fmaxf(rmax, __shfl_xor(rmax, 16, 64));
        rmax = fmaxf(rmax, __shfl_xor(rmax, 32, 64));

        const float mnew = fmaxf(m_r, rmax);
        const float scale = __expf(m_r - mnew);
        m_r = mnew;

        float psum = 0.f;
        u16 ph[4][4];
#pragma unroll
        for (int kn = 0; kn < 4; ++kn)
#pragma unroll
            for (int r = 0; r < 4; ++r) {
                const float p = __expf(s[kn][r] - mnew);
                psum += p;
                ph[kn][r] = f2bf(p);
            }
        psum += __shfl_xor(psum, 16, 64);
        psum += __shfl_xor(psum, 32, 64);
        l_r = l_r * scale + psum;

#pragma unroll
        for (int nd = 0; nd < 4; ++nd)
#pragma unroll
            for (int r = 0; r < 4; ++r)
                o_acc[nd][r] *= scale;

        // PV B-frag: keys 32ks+8g+e  ==  [p[2ks][0..3], p[2ks+1][0..3]]
        bf16x8 pf[2];
#pragma unroll
        for (int ks = 0; ks < 2; ++ks) {
            union { bf16x8 v; u16 e[8]; } u;
#pragma unroll
            for (int r = 0; r < 4; ++r) { u.e[r] = ph[2*ks][r]; u.e[4+r] = ph[2*ks+1][r]; }
            pf[ks] = u.v;
        }
#pragma unroll
        for (int nd = 0; nd < 4; ++nd) {
            o_acc[nd] = __builtin_amdgcn_mfma_f32_16x16x32_bf16(vf[nd][0], pf[0], o_acc[nd], 0, 0, 0);
            o_acc[nd] = __builtin_amdgcn_mfma_f32_16x16x32_bf16(vf[nd][1], pf[1], o_acc[nd], 0, 0, 0);
        }
    }

    const float inv = 1.0f / l_r;
#pragma unroll
    for (int nd = 0; nd < 4; ++nd) {
        ushort4 pk;
        pk.x = f2bf(o_acc[nd][0] * inv);
        pk.y = f2bf(o_acc[nd][1] * inv);
        pk.z = f2bf(o_acc[nd][2] * inv);
        pk.w = f2bf(o_acc[nd][3] * inv);
        *(ushort4*)(ctx + (size_t)qrow * 1024 + h*64 + nd*16 + g*4) = pk;
    }
}

// ---------------------------------------------------------------------------
extern "C" void kernel_launch(void* const* d_in, const int* in_sizes, int n_in,
                              void* d_out, int out_size, void* d_ws, size_t ws_size,
                              hipStream_t stream)
{
    (void)in_sizes; (void)n_in; (void)out_size; (void)ws_size;
    const float* hidden  = (const float*)d_in[0];
    const float* alibi   = (const float*)d_in[2];
    const float* ln1_g   = (const float*)d_in[3];
    const float* ln1_b   = (const float*)d_in[4];
    const float* qkv_w   = (const float*)d_in[5];
    const float* qkv_b   = (const float*)d_in[6];
    const float* dense_w = (const float*)d_in[7];
    const float* dense_b = (const float*)d_in[8];
    const float* ln2_g   = (const float*)d_in[9];
    const float* ln2_b   = (const float*)d_in[10];
    const float* fc1_w   = (const float*)d_in[11];
    const float* fc1_b   = (const float*)d_in[12];
    const float* fc2_w   = (const float*)d_in[13];
    const float* fc2_b   = (const float*)d_in[14];
    float* out = (float*)d_out;

    char* p = (char*)d_ws;
    u16* ln_buf   = (u16*)p;  p += (size_t)2048 * 1024 * 2;
    u16* qkv_wb   = (u16*)p;  p += (size_t)3072 * 1024 * 2;
    u16* fusedq   = (u16*)p;  p += (size_t)2048 * 3072 * 2;
    u16* ctx      = (u16*)p;  p += (size_t)2048 * 1024 * 2;
    u16* dense_wb = (u16*)p;  p += (size_t)1024 * 1024 * 2;
    float* attn_o = (float*)p; p += (size_t)2048 * 1024 * 4;
    u16* fc1_wb   = (u16*)p;  p += (size_t)4096 * 1024 * 2;
    u16* fc2_wb   = (u16*)p;  p += (size_t)1024 * 4096 * 2;
    u16* hbuf = fusedq;          // FC1 out (16MB) aliases fusedq+ctx (dead)
    u16* vT   = (u16*)attn_o;    // vT (4MB) aliases attn_o (written after attn)

    cvt_f32_bf16<<<2048, 256, 0, stream>>>(qkv_w,   qkv_wb,   3072*1024/4);
    cvt_f32_bf16<<<1024, 256, 0, stream>>>(dense_w, dense_wb, 1024*1024/4);
    cvt_f32_bf16<<<2048, 256, 0, stream>>>(fc1_w,   fc1_wb,   4096*1024/4);
    cvt_f32_bf16<<<2048, 256, 0, stream>>>(fc2_w,   fc2_wb,   1024*4096/4);

    ln_bf16<<<2048, 256, 0, stream>>>(hidden, ln1_g, ln1_b, ln_buf);
    // QKV: writes fused + transposed V copy
    gemm_bt<3,128><<<dim3(16, 24), 256, 0, stream>>>(ln_buf, qkv_wb, qkv_b, nullptr, fusedq, vT, 2048, 3072, 1024);
    attn_swapped<<<2048, 64, 0, stream>>>(fusedq, vT, alibi, ctx);
    gemm_bt<1,64><<<dim3(16, 16), 256, 0, stream>>>(ctx, dense_wb, dense_b, hidden, attn_o, nullptr, 2048, 1024, 1024);
    ln_bf16<<<2048, 256, 0, stream>>>(attn_o, ln2_g, ln2_b, ln_buf);
    gemm_bt<2,128><<<dim3(16, 32), 256, 0, stream>>>(ln_buf, fc1_wb, fc1_b, nullptr, hbuf, nullptr, 2048, 4096, 1024);
    gemm_bt<1,64><<<dim3(16, 16), 256, 0, stream>>>(hbuf, fc2_wb, fc2_b, attn_o, out, nullptr, 2048, 1024, 4096);
}

// Round 3
// 238.709 us; speedup vs baseline: 1.2194x; 1.0409x over previous
//
#include <hip/hip_runtime.h>
#include <hip/hip_bf16.h>

typedef unsigned short u16;
typedef __attribute__((ext_vector_type(8))) short bf16x8;
typedef __attribute__((ext_vector_type(4))) float f32x4;

typedef __attribute__((address_space(1))) const void cgvoid;
typedef __attribute__((address_space(3))) void lvoid;

static __device__ __forceinline__ u16 f2bf(float x) {
    __hip_bfloat16 h = __float2bfloat16(x);
    return __builtin_bit_cast(u16, h);
}

static __device__ __forceinline__ void gload_lds16(const u16* g, u16* l) {
    __builtin_amdgcn_global_load_lds((cgvoid*)g, (lvoid*)l, 16, 0, 0);
}

// ---------------------------------------------------------------------------
// fp32 -> bf16 elementwise convert
// ---------------------------------------------------------------------------
__global__ __launch_bounds__(256) void cvt_f32_bf16(
    const float* __restrict__ in, u16* __restrict__ out, int n4)
{
    int i = blockIdx.x * blockDim.x + threadIdx.x;
    const int stride = gridDim.x * blockDim.x;
    for (; i < n4; i += stride) {
        const float4 v = ((const float4*)in)[i];
        ushort4 pk;
        pk.x = f2bf(v.x); pk.y = f2bf(v.y); pk.z = f2bf(v.z); pk.w = f2bf(v.w);
        ((ushort4*)out)[i] = pk;
    }
}

// ---------------------------------------------------------------------------
// LayerNorm over H=1024, one block per row, bf16 out
// ---------------------------------------------------------------------------
__global__ __launch_bounds__(256) void ln_bf16(
    const float* __restrict__ x, const float* __restrict__ gw,
    const float* __restrict__ bw, u16* __restrict__ out)
{
    const int row = blockIdx.x;
    const int t = threadIdx.x;
    const float4 v = ((const float4*)(x + (size_t)row * 1024))[t];
    float s  = v.x + v.y + v.z + v.w;
    float sq = v.x*v.x + v.y*v.y + v.z*v.z + v.w*v.w;
#pragma unroll
    for (int d = 1; d < 64; d <<= 1) {
        s  += __shfl_xor(s, d, 64);
        sq += __shfl_xor(sq, d, 64);
    }
    __shared__ float ss[4], ssq[4];
    const int wave = t >> 6, lane = t & 63;
    if (lane == 0) { ss[wave] = s; ssq[wave] = sq; }
    __syncthreads();
    s  = ss[0] + ss[1] + ss[2] + ss[3];
    sq = ssq[0] + ssq[1] + ssq[2] + ssq[3];
    const float mu = s * (1.f / 1024.f);
    const float rinv = rsqrtf(sq * (1.f / 1024.f) - mu * mu + 1e-5f);
    const float4 gv = ((const float4*)gw)[t];
    const float4 bv = ((const float4*)bw)[t];
    ushort4 pk;
    pk.x = f2bf((v.x - mu) * rinv * gv.x + bv.x);
    pk.y = f2bf((v.y - mu) * rinv * gv.y + bv.y);
    pk.z = f2bf((v.z - mu) * rinv * gv.z + bv.z);
    pk.w = f2bf((v.w - mu) * rinv * gv.w + bv.w);
    ((ushort4*)(out + (size_t)row * 1024))[t] = pk;
}

// ---------------------------------------------------------------------------
// C[M][N] = A[M][K] @ W[N][K]^T + bias (+ epilogue)
// BM=128, BN in {64,128}, BK=64, 4 waves.
// EPI: 0 = bf16 out, 1 = f32 out + residual, 2 = bf16 out + bloom-gelu,
//      3 = bf16 out + transposed copy of V columns (QKV epilogue)
// ---------------------------------------------------------------------------
template<int EPI, int BN>
__global__ __launch_bounds__(256) void gemm_bt(
    const u16* __restrict__ A, const u16* __restrict__ Bw,
    const float* __restrict__ bias, const float* __restrict__ res,
    void* __restrict__ Cout, u16* __restrict__ vTout, int M, int N, int K)
{
    constexpr int WC = BN / 64;
    constexpr int MI = (BN == 128) ? 4 : 2;
    constexpr int NI = 4;
    __shared__ __align__(16) u16 As[128 * 64];
    __shared__ __align__(16) u16 Bs[BN * 64];
    const int t = threadIdx.x;
    const int lane = t & 63;
    const int wave = t >> 6;
    const int wr = wave / WC, wc = wave % WC;
    const int g = lane >> 4, r16 = lane & 15;
    const int tile_m = blockIdx.x * 128;
    const int tile_n = blockIdx.y * BN;

    f32x4 acc[MI][NI] = {};

    for (int k0 = 0; k0 < K; k0 += 64) {
        __syncthreads();
#pragma unroll
        for (int i = 0; i < 4; ++i) {
            const int off = (t + i * 256) * 8;
            const int row = off >> 6;
            const int col = off & 63;
            gload_lds16(A + (size_t)(tile_m + row) * K + k0 + col, As + off);
        }
#pragma unroll
        for (int i = 0; i < BN / 32; ++i) {
            const int off = (t + i * 256) * 8;
            const int row = off >> 6;
            const int col = off & 63;
            gload_lds16(Bw + (size_t)(tile_n + row) * K + k0 + col, Bs + off);
        }
        __syncthreads();

        bf16x8 af[MI][2], bfr[NI][2];
#pragma unroll
        for (int mi = 0; mi < MI; ++mi)
#pragma unroll
            for (int ks = 0; ks < 2; ++ks)
                af[mi][ks] = *(const bf16x8*)(As + (wr*(MI*16) + mi*16 + r16)*64 + ks*32 + g*8);
#pragma unroll
        for (int ni = 0; ni < NI; ++ni)
#pragma unroll
            for (int ks = 0; ks < 2; ++ks)
                bfr[ni][ks] = *(const bf16x8*)(Bs + (wc*64 + ni*16 + r16)*64 + ks*32 + g*8);
#pragma unroll
        for (int mi = 0; mi < MI; ++mi)
#pragma unroll
            for (int ni = 0; ni < NI; ++ni) {
                acc[mi][ni] = __builtin_amdgcn_mfma_f32_16x16x32_bf16(af[mi][0], bfr[ni][0], acc[mi][ni], 0, 0, 0);
                acc[mi][ni] = __builtin_amdgcn_mfma_f32_16x16x32_bf16(af[mi][1], bfr[ni][1], acc[mi][ni], 0, 0, 0);
            }
    }

#pragma unroll
    for (int mi = 0; mi < MI; ++mi) {
#pragma unroll
        for (int ni = 0; ni < NI; ++ni) {
            const int col = tile_n + wc*64 + ni*16 + r16;
            const float bv = bias[col];
            const int row0 = tile_m + wr*(MI*16) + mi*16 + g*4;
            float vv[4];
#pragma unroll
            for (int r = 0; r < 4; ++r) vv[r] = acc[mi][ni][r] + bv;
#pragma unroll
            for (int r = 0; r < 4; ++r) {
                const int row = row0 + r;
                if constexpr (EPI == 0 || EPI == 3) {
                    ((u16*)Cout)[(size_t)row * N + col] = f2bf(vv[r]);
                } else if constexpr (EPI == 1) {
                    ((float*)Cout)[(size_t)row * N + col] = vv[r] + res[(size_t)row * N + col];
                } else {
                    const float x = vv[r];
                    const float c = 0.79788456f * x * (1.0f + 0.044715f * x * x);
                    ((u16*)Cout)[(size_t)row * N + col] = f2bf(x / (1.0f + __expf(-2.0f * c)));
                }
            }
            if constexpr (EPI == 3) {
                if (((col >> 6) % 3) == 2) {
                    const int h = col / 192;
                    const int d = (col % 192) - 128;
                    ushort4 pk;
                    pk.x = f2bf(vv[0]); pk.y = f2bf(vv[1]);
                    pk.z = f2bf(vv[2]); pk.w = f2bf(vv[3]);
                    *(ushort4*)(vTout + ((size_t)(h*64 + d)) * 2048 + row0) = pk;
                }
            }
        }
    }
}

// ---------------------------------------------------------------------------
// Swapped-operand flash attention with 4-way K-split (flash-decode style).
// Block = 256 thr = 4 waves; each block owns (head h, 16 q-rows). Wave w
// processes K-tiles kt = w, w+4, ... with private online-softmax state;
// partials merged through LDS at the end. No LDS in the main loop.
// ---------------------------------------------------------------------------
__global__ __launch_bounds__(256, 4) void attn_swapped(
    const u16* __restrict__ fused, const u16* __restrict__ vT,
    const float* __restrict__ alibi, u16* __restrict__ ctx)
{
    const int bid = blockIdx.x;
    const int h = bid & 15;
    const int qt = 127 - (bid >> 4);        // heavy q-tiles dispatch first
    const int qw0 = qt * 16;
    const int t = threadIdx.x;
    const int lane = t & 63, wave = t >> 6;
    const int g = lane >> 4, r16 = lane & 15;
    const int qrow = qw0 + r16;

    __shared__ float Ms[4][16], Ls[4][16];
    __shared__ float Os[4][4][16][17];      // [wave][nd][d16][q] padded

    const u16* qbase = fused + (size_t)qrow * 3072 + h * 192;
    bf16x8 qf[2];
    qf[0] = *(const bf16x8*)(qbase + g*8);
    qf[1] = *(const bf16x8*)(qbase + 32 + g*8);

    int prow[4];
#pragma unroll
    for (int kn = 0; kn < 4; ++kn)
        prow[kn] = 32*(kn>>1) + 8*(r16>>2) + 4*(kn&1) + (r16&3);

    f32x4 o_acc[4] = {};
    float m_r = -3.0e38f, l_r = 0.f;

    const u16* kbase = fused + h*192 + 64;
    const u16* vbase = vT + (size_t)h * 64 * 2048;
    const float* abase = alibi + (size_t)h * 2048;

    const int nkt = (qw0 >> 6) + 1;
    for (int kt = wave; kt < nkt; kt += 4) {
        const int kt0 = kt * 64;

        // all loads issued up front (independent): K frags, alibi, V frags
        bf16x8 kf[4][2];
#pragma unroll
        for (int kn = 0; kn < 4; ++kn) {
            const u16* kr = kbase + (size_t)(kt0 + prow[kn]) * 3072;
            kf[kn][0] = *(const bf16x8*)(kr + g*8);
            kf[kn][1] = *(const bf16x8*)(kr + 32 + g*8);
        }
        float4 al[4];
#pragma unroll
        for (int kn = 0; kn < 4; ++kn)
            al[kn] = *(const float4*)(abase + kt0 + 32*(kn>>1) + 8*g + 4*(kn&1));
        bf16x8 vf[4][2];
#pragma unroll
        for (int nd = 0; nd < 4; ++nd) {
            const u16* vr = vbase + (size_t)(nd*16 + r16) * 2048 + kt0;
            vf[nd][0] = *(const bf16x8*)(vr + g*8);
            vf[nd][1] = *(const bf16x8*)(vr + 32 + g*8);
        }

        // S^T = K @ Q^T : lane holds 16 keys for its q-row
        f32x4 sc[4] = {};
#pragma unroll
        for (int kn = 0; kn < 4; ++kn) {
            sc[kn] = __builtin_amdgcn_mfma_f32_16x16x32_bf16(kf[kn][0], qf[0], sc[kn], 0, 0, 0);
            sc[kn] = __builtin_amdgcn_mfma_f32_16x16x32_bf16(kf[kn][1], qf[1], sc[kn], 0, 0, 0);
        }

        float s[4][4];
        float rmax = -3.0e38f;
#pragma unroll
        for (int kn = 0; kn < 4; ++kn) {
            const int kb = kt0 + 32*(kn>>1) + 8*g + 4*(kn&1);
            const float alv[4] = {al[kn].x, al[kn].y, al[kn].z, al[kn].w};
#pragma unroll
            for (int r = 0; r < 4; ++r) {
                float v = sc[kn][r] * 0.125f + alv[r];
                v = (kb + r <= qrow) ? v : -1.0e30f;
                s[kn][r] = v;
                rmax = fmaxf(rmax, v);
            }
        }
        rmax = fmaxf(rmax, __shfl_xor(rmax, 16, 64));
        rmax = fmaxf(rmax, __shfl_xor(rmax, 32, 64));

        const float mnew = fmaxf(m_r, rmax);
        const float scale = __expf(m_r - mnew);
        m_r = mnew;

        float psum = 0.f;
        u16 ph[4][4];
#pragma unroll
        for (int kn = 0; kn < 4; ++kn)
#pragma unroll
            for (int r = 0; r < 4; ++r) {
                const float p = __expf(s[kn][r] - mnew);
                psum += p;
                ph[kn][r] = f2bf(p);
            }
        psum += __shfl_xor(psum, 16, 64);
        psum += __shfl_xor(psum, 32, 64);
        l_r = l_r * scale + psum;

#pragma unroll
        for (int nd = 0; nd < 4; ++nd)
#pragma unroll
            for (int r = 0; r < 4; ++r)
                o_acc[nd][r] *= scale;

        bf16x8 pf[2];
#pragma unroll
        for (int ks = 0; ks < 2; ++ks) {
            union { bf16x8 v; u16 e[8]; } u;
#pragma unroll
            for (int r = 0; r < 4; ++r) { u.e[r] = ph[2*ks][r]; u.e[4+r] = ph[2*ks+1][r]; }
            pf[ks] = u.v;
        }
#pragma unroll
        for (int nd = 0; nd < 4; ++nd) {
            o_acc[nd] = __builtin_amdgcn_mfma_f32_16x16x32_bf16(vf[nd][0], pf[0], o_acc[nd], 0, 0, 0);
            o_acc[nd] = __builtin_amdgcn_mfma_f32_16x16x32_bf16(vf[nd][1], pf[1], o_acc[nd], 0, 0, 0);
        }
    }

    // -------- merge 4 per-wave partials --------
#pragma unroll
    for (int nd = 0; nd < 4; ++nd)
#pragma unroll
        for (int r = 0; r < 4; ++r)
            Os[wave][nd][g*4 + r][r16] = o_acc[nd][r];
    if (g == 0) { Ms[wave][r16] = m_r; Ls[wave][r16] = l_r; }
    __syncthreads();

    if (wave == 0) {
        const float m0 = Ms[0][r16], m1 = Ms[1][r16], m2 = Ms[2][r16], m3 = Ms[3][r16];
        const float ms = fmaxf(fmaxf(m0, m1), fmaxf(m2, m3));
        const float f0 = __expf(m0 - ms), f1 = __expf(m1 - ms);
        const float f2 = __expf(m2 - ms), f3 = __expf(m3 - ms);
        const float l = f0*Ls[0][r16] + f1*Ls[1][r16] + f2*Ls[2][r16] + f3*Ls[3][r16];
        const float inv = 1.0f / l;
#pragma unroll
        for (int nd = 0; nd < 4; ++nd) {
            float v[4];
#pragma unroll
            for (int r = 0; r < 4; ++r) {
                const int d = g*4 + r;
                v[r] = (f0*Os[0][nd][d][r16] + f1*Os[1][nd][d][r16] +
                        f2*Os[2][nd][d][r16] + f3*Os[3][nd][d][r16]) * inv;
            }
            ushort4 pk;
            pk.x = f2bf(v[0]); pk.y = f2bf(v[1]); pk.z = f2bf(v[2]); pk.w = f2bf(v[3]);
            *(ushort4*)(ctx + (size_t)qrow * 1024 + h*64 + nd*16 + g*4) = pk;
        }
    }
}

// ---------------------------------------------------------------------------
extern "C" void kernel_launch(void* const* d_in, const int* in_sizes, int n_in,
                              void* d_out, int out_size, void* d_ws, size_t ws_size,
                              hipStream_t stream)
{
    (void)in_sizes; (void)n_in; (void)out_size; (void)ws_size;
    const float* hidden  = (const float*)d_in[0];
    const float* alibi   = (const float*)d_in[2];
    const float* ln1_g   = (const float*)d_in[3];
    const float* ln1_b   = (const float*)d_in[4];
    const float* qkv_w   = (const float*)d_in[5];
    const float* qkv_b   = (const float*)d_in[6];
    const float* dense_w = (const float*)d_in[7];
    const float* dense_b = (const float*)d_in[8];
    const float* ln2_g   = (const float*)d_in[9];
    const float* ln2_b   = (const float*)d_in[10];
    const float* fc1_w   = (const float*)d_in[11];
    const float* fc1_b   = (const float*)d_in[12];
    const float* fc2_w   = (const float*)d_in[13];
    const float* fc2_b   = (const float*)d_in[14];
    float* out = (float*)d_out;

    char* p = (char*)d_ws;
    u16* ln_buf   = (u16*)p;  p += (size_t)2048 * 1024 * 2;
    u16* qkv_wb   = (u16*)p;  p += (size_t)3072 * 1024 * 2;
    u16* fusedq   = (u16*)p;  p += (size_t)2048 * 3072 * 2;
    u16* ctx      = (u16*)p;  p += (size_t)2048 * 1024 * 2;
    u16* dense_wb = (u16*)p;  p += (size_t)1024 * 1024 * 2;
    float* attn_o = (float*)p; p += (size_t)2048 * 1024 * 4;
    u16* fc1_wb   = (u16*)p;  p += (size_t)4096 * 1024 * 2;
    u16* fc2_wb   = (u16*)p;  p += (size_t)1024 * 4096 * 2;
    u16* hbuf = fusedq;          // FC1 out (16MB) aliases fusedq+ctx (dead)
    u16* vT   = (u16*)attn_o;    // vT (4MB) aliases attn_o (written after attn)

    cvt_f32_bf16<<<2048, 256, 0, stream>>>(qkv_w,   qkv_wb,   3072*1024/4);
    cvt_f32_bf16<<<1024, 256, 0, stream>>>(dense_w, dense_wb, 1024*1024/4);
    cvt_f32_bf16<<<2048, 256, 0, stream>>>(fc1_w,   fc1_wb,   4096*1024/4);
    cvt_f32_bf16<<<2048, 256, 0, stream>>>(fc2_w,   fc2_wb,   1024*4096/4);

    ln_bf16<<<2048, 256, 0, stream>>>(hidden, ln1_g, ln1_b, ln_buf);
    gemm_bt<3,128><<<dim3(16, 24), 256, 0, stream>>>(ln_buf, qkv_wb, qkv_b, nullptr, fusedq, vT, 2048, 3072, 1024);
    attn_swapped<<<2048, 256, 0, stream>>>(fusedq, vT, alibi, ctx);
    gemm_bt<1,64><<<dim3(16, 16), 256, 0, stream>>>(ctx, dense_wb, dense_b, hidden, attn_o, nullptr, 2048, 1024, 1024);
    ln_bf16<<<2048, 256, 0, stream>>>(attn_o, ln2_g, ln2_b, ln_buf);
    gemm_bt<2,128><<<dim3(16, 32), 256, 0, stream>>>(ln_buf, fc1_wb, fc1_b, nullptr, hbuf, nullptr, 2048, 4096, 1024);
    gemm_bt<1,64><<<dim3(16, 16), 256, 0, stream>>>(hbuf, fc2_wb, fc2_b, attn_o, out, nullptr, 2048, 1024, 4096);
}

// Round 4
// 201.014 us; speedup vs baseline: 1.4481x; 1.1875x over previous
//
#include <hip/hip_runtime.h>
#include <hip/hip_bf16.h>

typedef unsigned short u16;
typedef __attribute__((ext_vector_type(8))) short bf16x8;
typedef __attribute__((ext_vector_type(4))) float f32x4;

typedef __attribute__((address_space(1))) const void cgvoid;
typedef __attribute__((address_space(3))) void lvoid;

static __device__ __forceinline__ u16 f2bf(float x) {
    __hip_bfloat16 h = __float2bfloat16(x);
    return __builtin_bit_cast(u16, h);
}

static __device__ __forceinline__ void gload_lds16(const u16* g, u16* l) {
    __builtin_amdgcn_global_load_lds((cgvoid*)g, (lvoid*)l, 16, 0, 0);
}

// ---------------------------------------------------------------------------
// fp32 -> bf16 elementwise convert
// ---------------------------------------------------------------------------
__global__ __launch_bounds__(256) void cvt_f32_bf16(
    const float* __restrict__ in, u16* __restrict__ out, int n4)
{
    int i = blockIdx.x * blockDim.x + threadIdx.x;
    const int stride = gridDim.x * blockDim.x;
    for (; i < n4; i += stride) {
        const float4 v = ((const float4*)in)[i];
        ushort4 pk;
        pk.x = f2bf(v.x); pk.y = f2bf(v.y); pk.z = f2bf(v.z); pk.w = f2bf(v.w);
        ((ushort4*)out)[i] = pk;
    }
}

// ---------------------------------------------------------------------------
// LayerNorm over H=1024, one block per row, bf16 out
// ---------------------------------------------------------------------------
__global__ __launch_bounds__(256) void ln_bf16(
    const float* __restrict__ x, const float* __restrict__ gw,
    const float* __restrict__ bw, u16* __restrict__ out)
{
    const int row = blockIdx.x;
    const int t = threadIdx.x;
    const float4 v = ((const float4*)(x + (size_t)row * 1024))[t];
    float s  = v.x + v.y + v.z + v.w;
    float sq = v.x*v.x + v.y*v.y + v.z*v.z + v.w*v.w;
#pragma unroll
    for (int d = 1; d < 64; d <<= 1) {
        s  += __shfl_xor(s, d, 64);
        sq += __shfl_xor(sq, d, 64);
    }
    __shared__ float ss[4], ssq[4];
    const int wave = t >> 6, lane = t & 63;
    if (lane == 0) { ss[wave] = s; ssq[wave] = sq; }
    __syncthreads();
    s  = ss[0] + ss[1] + ss[2] + ss[3];
    sq = ssq[0] + ssq[1] + ssq[2] + ssq[3];
    const float mu = s * (1.f / 1024.f);
    const float rinv = rsqrtf(sq * (1.f / 1024.f) - mu * mu + 1e-5f);
    const float4 gv = ((const float4*)gw)[t];
    const float4 bv = ((const float4*)bw)[t];
    ushort4 pk;
    pk.x = f2bf((v.x - mu) * rinv * gv.x + bv.x);
    pk.y = f2bf((v.y - mu) * rinv * gv.y + bv.y);
    pk.z = f2bf((v.z - mu) * rinv * gv.z + bv.z);
    pk.w = f2bf((v.w - mu) * rinv * gv.w + bv.w);
    ((ushort4*)(out + (size_t)row * 1024))[t] = pk;
}

// ---------------------------------------------------------------------------
// C[M][N] = A[M][K] @ W[N][K]^T + bias (+ epilogue)
// BM=128, BN in {64,128}, BK=64, 4 waves.
// EPI: 0 = bf16 out, 1 = f32 out + residual, 2 = bf16 out + bloom-gelu
// ---------------------------------------------------------------------------
template<int EPI, int BN>
__global__ __launch_bounds__(256) void gemm_bt(
    const u16* __restrict__ A, const u16* __restrict__ Bw,
    const float* __restrict__ bias, const float* __restrict__ res,
    void* __restrict__ Cout, int M, int N, int K)
{
    constexpr int WC = BN / 64;
    constexpr int MI = (BN == 128) ? 4 : 2;
    constexpr int NI = 4;
    __shared__ __align__(16) u16 As[128 * 64];
    __shared__ __align__(16) u16 Bs[BN * 64];
    const int t = threadIdx.x;
    const int lane = t & 63;
    const int wave = t >> 6;
    const int wr = wave / WC, wc = wave % WC;
    const int g = lane >> 4, r16 = lane & 15;
    const int tile_m = blockIdx.x * 128;
    const int tile_n = blockIdx.y * BN;

    f32x4 acc[MI][NI] = {};

    for (int k0 = 0; k0 < K; k0 += 64) {
        __syncthreads();
#pragma unroll
        for (int i = 0; i < 4; ++i) {
            const int off = (t + i * 256) * 8;
            const int row = off >> 6;
            const int col = off & 63;
            gload_lds16(A + (size_t)(tile_m + row) * K + k0 + col, As + off);
        }
#pragma unroll
        for (int i = 0; i < BN / 32; ++i) {
            const int off = (t + i * 256) * 8;
            const int row = off >> 6;
            const int col = off & 63;
            gload_lds16(Bw + (size_t)(tile_n + row) * K + k0 + col, Bs + off);
        }
        __syncthreads();

        bf16x8 af[MI][2], bfr[NI][2];
#pragma unroll
        for (int mi = 0; mi < MI; ++mi)
#pragma unroll
            for (int ks = 0; ks < 2; ++ks)
                af[mi][ks] = *(const bf16x8*)(As + (wr*(MI*16) + mi*16 + r16)*64 + ks*32 + g*8);
#pragma unroll
        for (int ni = 0; ni < NI; ++ni)
#pragma unroll
            for (int ks = 0; ks < 2; ++ks)
                bfr[ni][ks] = *(const bf16x8*)(Bs + (wc*64 + ni*16 + r16)*64 + ks*32 + g*8);
#pragma unroll
        for (int mi = 0; mi < MI; ++mi)
#pragma unroll
            for (int ni = 0; ni < NI; ++ni) {
                acc[mi][ni] = __builtin_amdgcn_mfma_f32_16x16x32_bf16(af[mi][0], bfr[ni][0], acc[mi][ni], 0, 0, 0);
                acc[mi][ni] = __builtin_amdgcn_mfma_f32_16x16x32_bf16(af[mi][1], bfr[ni][1], acc[mi][ni], 0, 0, 0);
            }
    }

#pragma unroll
    for (int mi = 0; mi < MI; ++mi) {
#pragma unroll
        for (int ni = 0; ni < NI; ++ni) {
            const int col = tile_n + wc*64 + ni*16 + r16;
            const float bv = bias[col];
            const int row0 = tile_m + wr*(MI*16) + mi*16 + g*4;
#pragma unroll
            for (int r = 0; r < 4; ++r) {
                const int row = row0 + r;
                const float v = acc[mi][ni][r] + bv;
                if constexpr (EPI == 0) {
                    ((u16*)Cout)[(size_t)row * N + col] = f2bf(v);
                } else if constexpr (EPI == 1) {
                    ((float*)Cout)[(size_t)row * N + col] = v + res[(size_t)row * N + col];
                } else {
                    const float c = 0.79788456f * v * (1.0f + 0.044715f * v * v);
                    ((u16*)Cout)[(size_t)row * N + col] = f2bf(v / (1.0f + __expf(-2.0f * c)));
                }
            }
        }
    }
}

// ---------------------------------------------------------------------------
// Pack K and V into MFMA-fragment order (gather once, reuse ~64x).
// kP/vP layout: [h][kt][gi=0..7][lane=0..63][e=0..7] (u16), 8KB per (h,kt).
//   kP: gi=(kn,ks): lane(g,r16) holds K[kt0+prow(kn,r16)][ks*32+g*8+e]
//   vP: gi=(nd,ks): lane(g,r16) holds V[kt0+ks*32+g*8+e][nd*16+r16]
// grid = 512 blocks (16 heads x 32 tiles), 256 threads.
// ---------------------------------------------------------------------------
__global__ __launch_bounds__(256) void pack_kv(
    const u16* __restrict__ fused, u16* __restrict__ kP, u16* __restrict__ vP)
{
    const int bid = blockIdx.x;
    const int h = bid >> 5, kt = bid & 31;
    const int kt0 = kt * 64;
    const int t = threadIdx.x;
    const int lane = t & 63;
    const int g = lane >> 4, r16 = lane & 15;
    const size_t tbase = ((size_t)(h * 32 + kt)) * 4096;

#pragma unroll
    for (int half = 0; half < 2; ++half) {
        const int gi = (t >> 6) + half * 4;          // 0..7
        const int kn = gi >> 1, ks = gi & 1;
        // K fragment chunk (16B vector gather)
        const int w = 32*(kn>>1) + 8*(r16>>2) + 4*(kn&1) + (r16&3);
        const bf16x8 kv = *(const bf16x8*)(fused + (size_t)(kt0 + w) * 3072 + h*192 + 64 + ks*32 + g*8);
        *(bf16x8*)(kP + tbase + gi*512 + lane*8) = kv;
        // V fragment chunk (8 scalar u16 gathers along token dim)
        union { bf16x8 v; u16 e[8]; } uv;
        const u16* vs = fused + (size_t)(kt0 + ks*32 + g*8) * 3072 + h*192 + 128 + kn*16 + r16;
#pragma unroll
        for (int e = 0; e < 8; ++e) uv.e[e] = vs[(size_t)e * 3072];
        *(bf16x8*)(vP + tbase + gi*512 + lane*8) = uv.v;
    }
}

// ---------------------------------------------------------------------------
// Swapped-operand flash attention, 4-way K-split, fragment-packed K/V.
// Block = 4 waves; block owns (head h, 16 q-rows). Wave w does kt = w, w+4...
// All fragment loads are lane-linear 1KB coalesced reads from kP/vP.
// ---------------------------------------------------------------------------
__global__ __launch_bounds__(256, 4) void attn_swapped(
    const u16* __restrict__ fused, const u16* __restrict__ kP,
    const u16* __restrict__ vP, const float* __restrict__ alibi,
    u16* __restrict__ ctx)
{
    const int bid = blockIdx.x;
    const int h = bid & 15;
    const int qt = 127 - (bid >> 4);        // heavy q-tiles dispatch first
    const int qw0 = qt * 16;
    const int t = threadIdx.x;
    const int lane = t & 63, wave = t >> 6;
    const int g = lane >> 4, r16 = lane & 15;
    const int qrow = qw0 + r16;

    __shared__ float Ms[4][16], Ls[4][16];
    __shared__ float Os[4][4][16][17];      // [wave][nd][d16][q] padded

    const u16* qbase = fused + (size_t)qrow * 3072 + h * 192;
    bf16x8 qf[2];
    qf[0] = *(const bf16x8*)(qbase + g*8);
    qf[1] = *(const bf16x8*)(qbase + 32 + g*8);

    f32x4 o_acc[4] = {};
    float m_r = -3.0e38f, l_r = 0.f;

    const u16* kPh = kP + (size_t)h * 32 * 4096;
    const u16* vPh = vP + (size_t)h * 32 * 4096;
    const float* abase = alibi + (size_t)h * 2048;

    const int nkt = (qw0 >> 6) + 1;
    for (int kt = wave; kt < nkt; kt += 4) {
        const int kt0 = kt * 64;
        const u16* kT = kPh + (size_t)kt * 4096;
        const u16* vT = vPh + (size_t)kt * 4096;

        // coalesced fragment loads (issued up front)
        bf16x8 kf[4][2], vf[4][2];
#pragma unroll
        for (int kn = 0; kn < 4; ++kn) {
            kf[kn][0] = *(const bf16x8*)(kT + (kn*2 + 0)*512 + lane*8);
            kf[kn][1] = *(const bf16x8*)(kT + (kn*2 + 1)*512 + lane*8);
        }
        float4 al[4];
#pragma unroll
        for (int kn = 0; kn < 4; ++kn)
            al[kn] = *(const float4*)(abase + kt0 + 32*(kn>>1) + 8*g + 4*(kn&1));
#pragma unroll
        for (int nd = 0; nd < 4; ++nd) {
            vf[nd][0] = *(const bf16x8*)(vT + (nd*2 + 0)*512 + lane*8);
            vf[nd][1] = *(const bf16x8*)(vT + (nd*2 + 1)*512 + lane*8);
        }

        // S^T = K @ Q^T : lane holds 16 keys for its q-row
        f32x4 sc[4] = {};
#pragma unroll
        for (int kn = 0; kn < 4; ++kn) {
            sc[kn] = __builtin_amdgcn_mfma_f32_16x16x32_bf16(kf[kn][0], qf[0], sc[kn], 0, 0, 0);
            sc[kn] = __builtin_amdgcn_mfma_f32_16x16x32_bf16(kf[kn][1], qf[1], sc[kn], 0, 0, 0);
        }

        float s[4][4];
        float rmax = -3.0e38f;
#pragma unroll
        for (int kn = 0; kn < 4; ++kn) {
            const int kb = kt0 + 32*(kn>>1) + 8*g + 4*(kn&1);
            const float alv[4] = {al[kn].x, al[kn].y, al[kn].z, al[kn].w};
#pragma unroll
            for (int r = 0; r < 4; ++r) {
                float v = sc[kn][r] * 0.125f + alv[r];
                v = (kb + r <= qrow) ? v : -1.0e30f;
                s[kn][r] = v;
                rmax = fmaxf(rmax, v);
            }
        }
        rmax = fmaxf(rmax, __shfl_xor(rmax, 16, 64));
        rmax = fmaxf(rmax, __shfl_xor(rmax, 32, 64));

        const float mnew = fmaxf(m_r, rmax);
        const float scale = __expf(m_r - mnew);
        m_r = mnew;

        float psum = 0.f;
        u16 ph[4][4];
#pragma unroll
        for (int kn = 0; kn < 4; ++kn)
#pragma unroll
            for (int r = 0; r < 4; ++r) {
                const float p = __expf(s[kn][r] - mnew);
                psum += p;
                ph[kn][r] = f2bf(p);
            }
        psum += __shfl_xor(psum, 16, 64);
        psum += __shfl_xor(psum, 32, 64);
        l_r = l_r * scale + psum;

#pragma unroll
        for (int nd = 0; nd < 4; ++nd)
#pragma unroll
            for (int r = 0; r < 4; ++r)
                o_acc[nd][r] *= scale;

        bf16x8 pf[2];
#pragma unroll
        for (int ks = 0; ks < 2; ++ks) {
            union { bf16x8 v; u16 e[8]; } u;
#pragma unroll
            for (int r = 0; r < 4; ++r) { u.e[r] = ph[2*ks][r]; u.e[4+r] = ph[2*ks+1][r]; }
            pf[ks] = u.v;
        }
#pragma unroll
        for (int nd = 0; nd < 4; ++nd) {
            o_acc[nd] = __builtin_amdgcn_mfma_f32_16x16x32_bf16(vf[nd][0], pf[0], o_acc[nd], 0, 0, 0);
            o_acc[nd] = __builtin_amdgcn_mfma_f32_16x16x32_bf16(vf[nd][1], pf[1], o_acc[nd], 0, 0, 0);
        }
    }

    // -------- merge 4 per-wave partials --------
#pragma unroll
    for (int nd = 0; nd < 4; ++nd)
#pragma unroll
        for (int r = 0; r < 4; ++r)
            Os[wave][nd][g*4 + r][r16] = o_acc[nd][r];
    if (g == 0) { Ms[wave][r16] = m_r; Ls[wave][r16] = l_r; }
    __syncthreads();

    if (wave == 0) {
        const float m0 = Ms[0][r16], m1 = Ms[1][r16], m2 = Ms[2][r16], m3 = Ms[3][r16];
        const float ms = fmaxf(fmaxf(m0, m1), fmaxf(m2, m3));
        const float f0 = __expf(m0 - ms), f1 = __expf(m1 - ms);
        const float f2 = __expf(m2 - ms), f3 = __expf(m3 - ms);
        const float l = f0*Ls[0][r16] + f1*Ls[1][r16] + f2*Ls[2][r16] + f3*Ls[3][r16];
        const float inv = 1.0f / l;
#pragma unroll
        for (int nd = 0; nd < 4; ++nd) {
            float v[4];
#pragma unroll
            for (int r = 0; r < 4; ++r) {
                const int d = g*4 + r;
                v[r] = (f0*Os[0][nd][d][r16] + f1*Os[1][nd][d][r16] +
                        f2*Os[2][nd][d][r16] + f3*Os[3][nd][d][r16]) * inv;
            }
            ushort4 pk;
            pk.x = f2bf(v[0]); pk.y = f2bf(v[1]); pk.z = f2bf(v[2]); pk.w = f2bf(v[3]);
            *(ushort4*)(ctx + (size_t)qrow * 1024 + h*64 + nd*16 + g*4) = pk;
        }
    }
}

// ---------------------------------------------------------------------------
extern "C" void kernel_launch(void* const* d_in, const int* in_sizes, int n_in,
                              void* d_out, int out_size, void* d_ws, size_t ws_size,
                              hipStream_t stream)
{
    (void)in_sizes; (void)n_in; (void)out_size; (void)ws_size;
    const float* hidden  = (const float*)d_in[0];
    const float* alibi   = (const float*)d_in[2];
    const float* ln1_g   = (const float*)d_in[3];
    const float* ln1_b   = (const float*)d_in[4];
    const float* qkv_w   = (const float*)d_in[5];
    const float* qkv_b   = (const float*)d_in[6];
    const float* dense_w = (const float*)d_in[7];
    const float* dense_b = (const float*)d_in[8];
    const float* ln2_g   = (const float*)d_in[9];
    const float* ln2_b   = (const float*)d_in[10];
    const float* fc1_w   = (const float*)d_in[11];
    const float* fc1_b   = (const float*)d_in[12];
    const float* fc2_w   = (const float*)d_in[13];
    const float* fc2_b   = (const float*)d_in[14];
    float* out = (float*)d_out;

    char* p = (char*)d_ws;
    u16* ln_buf   = (u16*)p;  p += (size_t)2048 * 1024 * 2;
    u16* qkv_wb   = (u16*)p;  p += (size_t)3072 * 1024 * 2;
    u16* fusedq   = (u16*)p;  p += (size_t)2048 * 3072 * 2;
    u16* ctx      = (u16*)p;  p += (size_t)2048 * 1024 * 2;
    u16* dense_wb = (u16*)p;  p += (size_t)1024 * 1024 * 2;
    float* attn_o = (float*)p; p += (size_t)2048 * 1024 * 4;
    u16* fc1_wb   = (u16*)p;  p += (size_t)4096 * 1024 * 2;
    u16* fc2_wb   = (u16*)p;  p += (size_t)1024 * 4096 * 2;
    u16* hbuf = fusedq;          // FC1 out (16MB) aliases fusedq+ctx (dead)
    u16* kP = (u16*)attn_o;      // 4MB, dead before dense writes attn_o
    u16* vP = kP + (size_t)16 * 32 * 4096;   // 4MB

    cvt_f32_bf16<<<2048, 256, 0, stream>>>(qkv_w,   qkv_wb,   3072*1024/4);
    cvt_f32_bf16<<<1024, 256, 0, stream>>>(dense_w, dense_wb, 1024*1024/4);
    cvt_f32_bf16<<<2048, 256, 0, stream>>>(fc1_w,   fc1_wb,   4096*1024/4);
    cvt_f32_bf16<<<2048, 256, 0, stream>>>(fc2_w,   fc2_wb,   1024*4096/4);

    ln_bf16<<<2048, 256, 0, stream>>>(hidden, ln1_g, ln1_b, ln_buf);
    gemm_bt<0,128><<<dim3(16, 24), 256, 0, stream>>>(ln_buf, qkv_wb, qkv_b, nullptr, fusedq, 2048, 3072, 1024);
    pack_kv<<<512, 256, 0, stream>>>(fusedq, kP, vP);
    attn_swapped<<<2048, 256, 0, stream>>>(fusedq, kP, vP, alibi, ctx);
    gemm_bt<1,64><<<dim3(16, 16), 256, 0, stream>>>(ctx, dense_wb, dense_b, hidden, attn_o, 2048, 1024, 1024);
    ln_bf16<<<2048, 256, 0, stream>>>(attn_o, ln2_g, ln2_b, ln_buf);
    gemm_bt<2,128><<<dim3(16, 32), 256, 0, stream>>>(ln_buf, fc1_wb, fc1_b, nullptr, hbuf, 2048, 4096, 1024);
    gemm_bt<1,64><<<dim3(16, 16), 256, 0, stream>>>(hbuf, fc2_wb, fc2_b, attn_o, out, 2048, 1024, 4096);
}

// Round 5
// 177.652 us; speedup vs baseline: 1.6385x; 1.1315x over previous
//
#include <hip/hip_runtime.h>
#include <hip/hip_bf16.h>

typedef unsigned short u16;
typedef __attribute__((ext_vector_type(8))) short bf16x8;
typedef __attribute__((ext_vector_type(4))) float f32x4;

typedef __attribute__((address_space(1))) const void cgvoid;
typedef __attribute__((address_space(3))) void lvoid;

static __device__ __forceinline__ u16 f2bf(float x) {
    __hip_bfloat16 h = __float2bfloat16(x);
    return __builtin_bit_cast(u16, h);
}

static __device__ __forceinline__ void gload_lds16(const u16* g, u16* l) {
    __builtin_amdgcn_global_load_lds((cgvoid*)g, (lvoid*)l, 16, 0, 0);
}

// ---------------------------------------------------------------------------
// fp32 -> bf16 elementwise convert
// ---------------------------------------------------------------------------
__global__ __launch_bounds__(256) void cvt_f32_bf16(
    const float* __restrict__ in, u16* __restrict__ out, int n4)
{
    int i = blockIdx.x * blockDim.x + threadIdx.x;
    const int stride = gridDim.x * blockDim.x;
    for (; i < n4; i += stride) {
        const float4 v = ((const float4*)in)[i];
        ushort4 pk;
        pk.x = f2bf(v.x); pk.y = f2bf(v.y); pk.z = f2bf(v.z); pk.w = f2bf(v.w);
        ((ushort4*)out)[i] = pk;
    }
}

// ---------------------------------------------------------------------------
// LayerNorm over H=1024, one block per row, bf16 out
// ---------------------------------------------------------------------------
__global__ __launch_bounds__(256) void ln_bf16(
    const float* __restrict__ x, const float* __restrict__ gw,
    const float* __restrict__ bw, u16* __restrict__ out)
{
    const int row = blockIdx.x;
    const int t = threadIdx.x;
    const float4 v = ((const float4*)(x + (size_t)row * 1024))[t];
    float s  = v.x + v.y + v.z + v.w;
    float sq = v.x*v.x + v.y*v.y + v.z*v.z + v.w*v.w;
#pragma unroll
    for (int d = 1; d < 64; d <<= 1) {
        s  += __shfl_xor(s, d, 64);
        sq += __shfl_xor(sq, d, 64);
    }
    __shared__ float ss[4], ssq[4];
    const int wave = t >> 6, lane = t & 63;
    if (lane == 0) { ss[wave] = s; ssq[wave] = sq; }
    __syncthreads();
    s  = ss[0] + ss[1] + ss[2] + ss[3];
    sq = ssq[0] + ssq[1] + ssq[2] + ssq[3];
    const float mu = s * (1.f / 1024.f);
    const float rinv = rsqrtf(sq * (1.f / 1024.f) - mu * mu + 1e-5f);
    const float4 gv = ((const float4*)gw)[t];
    const float4 bv = ((const float4*)bw)[t];
    ushort4 pk;
    pk.x = f2bf((v.x - mu) * rinv * gv.x + bv.x);
    pk.y = f2bf((v.y - mu) * rinv * gv.y + bv.y);
    pk.z = f2bf((v.z - mu) * rinv * gv.z + bv.z);
    pk.w = f2bf((v.w - mu) * rinv * gv.w + bv.w);
    ((ushort4*)(out + (size_t)row * 1024))[t] = pk;
}

// ---------------------------------------------------------------------------
// C[M][N] = A[M][K] @ W[N][K]^T (+ bias + epilogue)
// BM=128, BN in {64,128}, BK=64, 4 waves. blockIdx.z = K-split slice,
// each slice covers Kspan (= K / gridDim.z) of the K dim.
// EPI: 0 = bf16 out (+bias), 2 = bf16 out + bias + bloom-gelu,
//      4 = raw f32 partial (NO bias) to p0 (z==0) / pext[z-1]
// ---------------------------------------------------------------------------
template<int EPI, int BN>
__global__ __launch_bounds__(256, 4) void gemm_bt(
    const u16* __restrict__ A, const u16* __restrict__ Bw,
    const float* __restrict__ bias, void* __restrict__ Cout,
    float* __restrict__ p0, float* __restrict__ pext,
    int M, int N, int K, int Kspan)
{
    constexpr int WC = BN / 64;
    constexpr int MI = (BN == 128) ? 4 : 2;
    constexpr int NI = 4;
    __shared__ __align__(16) u16 As[128 * 64];
    __shared__ __align__(16) u16 Bs[BN * 64];
    const int t = threadIdx.x;
    const int lane = t & 63;
    const int wave = t >> 6;
    const int wr = wave / WC, wc = wave % WC;
    const int g = lane >> 4, r16 = lane & 15;
    const int tile_m = blockIdx.x * 128;
    const int tile_n = blockIdx.y * BN;
    const int kb = blockIdx.z * Kspan;

    f32x4 acc[MI][NI] = {};

    for (int k0 = kb; k0 < kb + Kspan; k0 += 64) {
        __syncthreads();
#pragma unroll
        for (int i = 0; i < 4; ++i) {
            const int off = (t + i * 256) * 8;
            const int row = off >> 6;
            const int col = off & 63;
            gload_lds16(A + (size_t)(tile_m + row) * K + k0 + col, As + off);
        }
#pragma unroll
        for (int i = 0; i < BN / 32; ++i) {
            const int off = (t + i * 256) * 8;
            const int row = off >> 6;
            const int col = off & 63;
            gload_lds16(Bw + (size_t)(tile_n + row) * K + k0 + col, Bs + off);
        }
        __syncthreads();

        bf16x8 af[MI][2], bfr[NI][2];
#pragma unroll
        for (int mi = 0; mi < MI; ++mi)
#pragma unroll
            for (int ks = 0; ks < 2; ++ks)
                af[mi][ks] = *(const bf16x8*)(As + (wr*(MI*16) + mi*16 + r16)*64 + ks*32 + g*8);
#pragma unroll
        for (int ni = 0; ni < NI; ++ni)
#pragma unroll
            for (int ks = 0; ks < 2; ++ks)
                bfr[ni][ks] = *(const bf16x8*)(Bs + (wc*64 + ni*16 + r16)*64 + ks*32 + g*8);
#pragma unroll
        for (int mi = 0; mi < MI; ++mi)
#pragma unroll
            for (int ni = 0; ni < NI; ++ni) {
                acc[mi][ni] = __builtin_amdgcn_mfma_f32_16x16x32_bf16(af[mi][0], bfr[ni][0], acc[mi][ni], 0, 0, 0);
                acc[mi][ni] = __builtin_amdgcn_mfma_f32_16x16x32_bf16(af[mi][1], bfr[ni][1], acc[mi][ni], 0, 0, 0);
            }
    }

    float* dst = nullptr;
    if constexpr (EPI == 4)
        dst = (blockIdx.z == 0) ? p0 : pext + (size_t)(blockIdx.z - 1) * ((size_t)M * N);

#pragma unroll
    for (int mi = 0; mi < MI; ++mi) {
#pragma unroll
        for (int ni = 0; ni < NI; ++ni) {
            const int col = tile_n + wc*64 + ni*16 + r16;
            const int row0 = tile_m + wr*(MI*16) + mi*16 + g*4;
#pragma unroll
            for (int r = 0; r < 4; ++r) {
                const int row = row0 + r;
                if constexpr (EPI == 4) {
                    dst[(size_t)row * N + col] = acc[mi][ni][r];
                } else if constexpr (EPI == 0) {
                    ((u16*)Cout)[(size_t)row * N + col] = f2bf(acc[mi][ni][r] + bias[col]);
                } else {
                    const float v = acc[mi][ni][r] + bias[col];
                    const float c = 0.79788456f * v * (1.0f + 0.044715f * v * v);
                    ((u16*)Cout)[(size_t)row * N + col] = f2bf(v / (1.0f + __expf(-2.0f * c)));
                }
            }
        }
    }
}

// ---------------------------------------------------------------------------
// out = p0 + sum(pext[j]) + bias + res   (f32, vectorized)
// ---------------------------------------------------------------------------
template<int NP>
__global__ __launch_bounds__(256) void reduce_bias_res(
    const float* __restrict__ p0, const float* __restrict__ pext,
    const float* __restrict__ bias, const float* __restrict__ res,
    float* __restrict__ out, int n4, int n4row)
{
    int i = blockIdx.x * blockDim.x + threadIdx.x;
    const int stride = gridDim.x * blockDim.x;
    for (; i < n4; i += stride) {
        float4 a = ((const float4*)p0)[i];
#pragma unroll
        for (int j = 0; j < NP - 1; ++j) {
            const float4 b = ((const float4*)pext)[(size_t)j * n4 + i];
            a.x += b.x; a.y += b.y; a.z += b.z; a.w += b.w;
        }
        const float4 bv = ((const float4*)bias)[i & (n4row - 1)];
        const float4 rv = ((const float4*)res)[i];
        float4 o;
        o.x = a.x + bv.x + rv.x;
        o.y = a.y + bv.y + rv.y;
        o.z = a.z + bv.z + rv.z;
        o.w = a.w + bv.w + rv.w;
        ((float4*)out)[i] = o;
    }
}

// ---------------------------------------------------------------------------
// Pack K and V into MFMA-fragment order (gather once, reuse ~64x).
// kP/vP layout: [h][kt][gi=0..7][lane=0..63][e=0..7] (u16), 8KB per (h,kt).
// ---------------------------------------------------------------------------
__global__ __launch_bounds__(256) void pack_kv(
    const u16* __restrict__ fused, u16* __restrict__ kP, u16* __restrict__ vP)
{
    const int bid = blockIdx.x;
    const int h = bid >> 5, kt = bid & 31;
    const int kt0 = kt * 64;
    const int t = threadIdx.x;
    const int lane = t & 63;
    const int g = lane >> 4, r16 = lane & 15;
    const size_t tbase = ((size_t)(h * 32 + kt)) * 4096;

#pragma unroll
    for (int half = 0; half < 2; ++half) {
        const int gi = (t >> 6) + half * 4;          // 0..7
        const int kn = gi >> 1, ks = gi & 1;
        const int w = 32*(kn>>1) + 8*(r16>>2) + 4*(kn&1) + (r16&3);
        const bf16x8 kv = *(const bf16x8*)(fused + (size_t)(kt0 + w) * 3072 + h*192 + 64 + ks*32 + g*8);
        *(bf16x8*)(kP + tbase + gi*512 + lane*8) = kv;
        union { bf16x8 v; u16 e[8]; } uv;
        const u16* vs = fused + (size_t)(kt0 + ks*32 + g*8) * 3072 + h*192 + 128 + kn*16 + r16;
#pragma unroll
        for (int e = 0; e < 8; ++e) uv.e[e] = vs[(size_t)e * 3072];
        *(bf16x8*)(vP + tbase + gi*512 + lane*8) = uv.v;
    }
}

// ---------------------------------------------------------------------------
// Swapped-operand flash attention, 4-way K-split, fragment-packed K/V.
// ---------------------------------------------------------------------------
__global__ __launch_bounds__(256, 4) void attn_swapped(
    const u16* __restrict__ fused, const u16* __restrict__ kP,
    const u16* __restrict__ vP, const float* __restrict__ alibi,
    u16* __restrict__ ctx)
{
    const int bid = blockIdx.x;
    const int h = bid & 15;
    const int qt = 127 - (bid >> 4);        // heavy q-tiles dispatch first
    const int qw0 = qt * 16;
    const int t = threadIdx.x;
    const int lane = t & 63, wave = t >> 6;
    const int g = lane >> 4, r16 = lane & 15;
    const int qrow = qw0 + r16;

    __shared__ float Ms[4][16], Ls[4][16];
    __shared__ float Os[4][4][16][17];      // [wave][nd][d16][q] padded

    const u16* qbase = fused + (size_t)qrow * 3072 + h * 192;
    bf16x8 qf[2];
    qf[0] = *(const bf16x8*)(qbase + g*8);
    qf[1] = *(const bf16x8*)(qbase + 32 + g*8);

    f32x4 o_acc[4] = {};
    float m_r = -3.0e38f, l_r = 0.f;

    const u16* kPh = kP + (size_t)h * 32 * 4096;
    const u16* vPh = vP + (size_t)h * 32 * 4096;
    const float* abase = alibi + (size_t)h * 2048;

    const int nkt = (qw0 >> 6) + 1;
    for (int kt = wave; kt < nkt; kt += 4) {
        const int kt0 = kt * 64;
        const u16* kT = kPh + (size_t)kt * 4096;
        const u16* vT = vPh + (size_t)kt * 4096;

        bf16x8 kf[4][2], vf[4][2];
#pragma unroll
        for (int kn = 0; kn < 4; ++kn) {
            kf[kn][0] = *(const bf16x8*)(kT + (kn*2 + 0)*512 + lane*8);
            kf[kn][1] = *(const bf16x8*)(kT + (kn*2 + 1)*512 + lane*8);
        }
        float4 al[4];
#pragma unroll
        for (int kn = 0; kn < 4; ++kn)
            al[kn] = *(const float4*)(abase + kt0 + 32*(kn>>1) + 8*g + 4*(kn&1));
#pragma unroll
        for (int nd = 0; nd < 4; ++nd) {
            vf[nd][0] = *(const bf16x8*)(vT + (nd*2 + 0)*512 + lane*8);
            vf[nd][1] = *(const bf16x8*)(vT + (nd*2 + 1)*512 + lane*8);
        }

        f32x4 sc[4] = {};
#pragma unroll
        for (int kn = 0; kn < 4; ++kn) {
            sc[kn] = __builtin_amdgcn_mfma_f32_16x16x32_bf16(kf[kn][0], qf[0], sc[kn], 0, 0, 0);
            sc[kn] = __builtin_amdgcn_mfma_f32_16x16x32_bf16(kf[kn][1], qf[1], sc[kn], 0, 0, 0);
        }

        float s[4][4];
        float rmax = -3.0e38f;
#pragma unroll
        for (int kn = 0; kn < 4; ++kn) {
            const int kb = kt0 + 32*(kn>>1) + 8*g + 4*(kn&1);
            const float alv[4] = {al[kn].x, al[kn].y, al[kn].z, al[kn].w};
#pragma unroll
            for (int r = 0; r < 4; ++r) {
                float v = sc[kn][r] * 0.125f + alv[r];
                v = (kb + r <= qrow) ? v : -1.0e30f;
                s[kn][r] = v;
                rmax = fmaxf(rmax, v);
            }
        }
        rmax = fmaxf(rmax, __shfl_xor(rmax, 16, 64));
        rmax = fmaxf(rmax, __shfl_xor(rmax, 32, 64));

        const float mnew = fmaxf(m_r, rmax);
        const float scale = __expf(m_r - mnew);
        m_r = mnew;

        float psum = 0.f;
        u16 ph[4][4];
#pragma unroll
        for (int kn = 0; kn < 4; ++kn)
#pragma unroll
            for (int r = 0; r < 4; ++r) {
                const float p = __expf(s[kn][r] - mnew);
                psum += p;
                ph[kn][r] = f2bf(p);
            }
        psum += __shfl_xor(psum, 16, 64);
        psum += __shfl_xor(psum, 32, 64);
        l_r = l_r * scale + psum;

#pragma unroll
        for (int nd = 0; nd < 4; ++nd)
#pragma unroll
            for (int r = 0; r < 4; ++r)
                o_acc[nd][r] *= scale;

        bf16x8 pf[2];
#pragma unroll
        for (int ks = 0; ks < 2; ++ks) {
            union { bf16x8 v; u16 e[8]; } u;
#pragma unroll
            for (int r = 0; r < 4; ++r) { u.e[r] = ph[2*ks][r]; u.e[4+r] = ph[2*ks+1][r]; }
            pf[ks] = u.v;
        }
#pragma unroll
        for (int nd = 0; nd < 4; ++nd) {
            o_acc[nd] = __builtin_amdgcn_mfma_f32_16x16x32_bf16(vf[nd][0], pf[0], o_acc[nd], 0, 0, 0);
            o_acc[nd] = __builtin_amdgcn_mfma_f32_16x16x32_bf16(vf[nd][1], pf[1], o_acc[nd], 0, 0, 0);
        }
    }

    // -------- merge 4 per-wave partials --------
#pragma unroll
    for (int nd = 0; nd < 4; ++nd)
#pragma unroll
        for (int r = 0; r < 4; ++r)
            Os[wave][nd][g*4 + r][r16] = o_acc[nd][r];
    if (g == 0) { Ms[wave][r16] = m_r; Ls[wave][r16] = l_r; }
    __syncthreads();

    if (wave == 0) {
        const float m0 = Ms[0][r16], m1 = Ms[1][r16], m2 = Ms[2][r16], m3 = Ms[3][r16];
        const float ms = fmaxf(fmaxf(m0, m1), fmaxf(m2, m3));
        const float f0 = __expf(m0 - ms), f1 = __expf(m1 - ms);
        const float f2 = __expf(m2 - ms), f3 = __expf(m3 - ms);
        const float l = f0*Ls[0][r16] + f1*Ls[1][r16] + f2*Ls[2][r16] + f3*Ls[3][r16];
        const float inv = 1.0f / l;
#pragma unroll
        for (int nd = 0; nd < 4; ++nd) {
            float v[4];
#pragma unroll
            for (int r = 0; r < 4; ++r) {
                const int d = g*4 + r;
                v[r] = (f0*Os[0][nd][d][r16] + f1*Os[1][nd][d][r16] +
                        f2*Os[2][nd][d][r16] + f3*Os[3][nd][d][r16]) * inv;
            }
            ushort4 pk;
            pk.x = f2bf(v[0]); pk.y = f2bf(v[1]); pk.z = f2bf(v[2]); pk.w = f2bf(v[3]);
            *(ushort4*)(ctx + (size_t)qrow * 1024 + h*64 + nd*16 + g*4) = pk;
        }
    }
}

// ---------------------------------------------------------------------------
extern "C" void kernel_launch(void* const* d_in, const int* in_sizes, int n_in,
                              void* d_out, int out_size, void* d_ws, size_t ws_size,
                              hipStream_t stream)
{
    (void)in_sizes; (void)n_in; (void)out_size; (void)ws_size;
    const float* hidden  = (const float*)d_in[0];
    const float* alibi   = (const float*)d_in[2];
    const float* ln1_g   = (const float*)d_in[3];
    const float* ln1_b   = (const float*)d_in[4];
    const float* qkv_w   = (const float*)d_in[5];
    const float* qkv_b   = (const float*)d_in[6];
    const float* dense_w = (const float*)d_in[7];
    const float* dense_b = (const float*)d_in[8];
    const float* ln2_g   = (const float*)d_in[9];
    const float* ln2_b   = (const float*)d_in[10];
    const float* fc1_w   = (const float*)d_in[11];
    const float* fc1_b   = (const float*)d_in[12];
    const float* fc2_w   = (const float*)d_in[13];
    const float* fc2_b   = (const float*)d_in[14];
    float* out = (float*)d_out;

    char* p = (char*)d_ws;
    u16* ln_buf   = (u16*)p;  p += (size_t)2048 * 1024 * 2;   // [0,4MB)
    u16* qkv_wb   = (u16*)p;  p += (size_t)3072 * 1024 * 2;   // [4,10)
    u16* fusedq   = (u16*)p;  p += (size_t)2048 * 3072 * 2;   // [10,22)
    u16* ctx      = (u16*)p;  p += (size_t)2048 * 1024 * 2;   // [22,26)
    u16* dense_wb = (u16*)p;  p += (size_t)1024 * 1024 * 2;   // [26,28)
    float* attn_o = (float*)p; p += (size_t)2048 * 1024 * 4;  // [28,36)
    u16* fc1_wb   = (u16*)p;  p += (size_t)4096 * 1024 * 2;   // [36,44)
    u16* fc2_wb   = (u16*)p;  p += (size_t)1024 * 4096 * 2;   // [44,52)
    float* pext   = (float*)p; p += (size_t)3 * 2048 * 1024 * 4; // [52,76) split-K partials 1..3
    u16* hbuf = fusedq;            // FC1 out (16MB) aliases fusedq+ctx (dead)
    u16* kP = (u16*)attn_o;        // 4MB, dead before dense-reduce writes attn_o
    u16* vP = kP + (size_t)16 * 32 * 4096;    // 4MB
    float* part0 = (float*)d_ws;   // 8MB over ln_buf+qkv_wb (dead at dense/FC2 time)

    cvt_f32_bf16<<<2048, 256, 0, stream>>>(qkv_w,   qkv_wb,   3072*1024/4);
    cvt_f32_bf16<<<1024, 256, 0, stream>>>(dense_w, dense_wb, 1024*1024/4);
    cvt_f32_bf16<<<2048, 256, 0, stream>>>(fc1_w,   fc1_wb,   4096*1024/4);
    cvt_f32_bf16<<<2048, 256, 0, stream>>>(fc2_w,   fc2_wb,   1024*4096/4);

    ln_bf16<<<2048, 256, 0, stream>>>(hidden, ln1_g, ln1_b, ln_buf);
    // QKV: 128x64 tiles, 768 blocks
    gemm_bt<0,64><<<dim3(16, 48), 256, 0, stream>>>(ln_buf, qkv_wb, qkv_b, fusedq,
                                                    nullptr, nullptr, 2048, 3072, 1024, 1024);
    pack_kv<<<512, 256, 0, stream>>>(fusedq, kP, vP);
    attn_swapped<<<2048, 256, 0, stream>>>(fusedq, kP, vP, alibi, ctx);
    // dense: split-K=2 (ln_buf/qkv_wb now dead -> part0 usable)
    gemm_bt<4,64><<<dim3(16, 16, 2), 256, 0, stream>>>(ctx, dense_wb, nullptr, nullptr,
                                                       part0, pext, 2048, 1024, 1024, 512);
    reduce_bias_res<2><<<2048, 256, 0, stream>>>(part0, pext, dense_b, hidden, attn_o,
                                                 2048*1024/4, 256);
    ln_bf16<<<2048, 256, 0, stream>>>(attn_o, ln2_g, ln2_b, ln_buf);
    // FC1: 128x64 tiles, 1024 blocks (reads ln_buf -- part0 region reused only after FC1)
    gemm_bt<2,64><<<dim3(16, 64), 256, 0, stream>>>(ln_buf, fc1_wb, fc1_b, hbuf,
                                                    nullptr, nullptr, 2048, 4096, 1024, 1024);
    // FC2: split-K=4, 1024 blocks (ln_buf dead again after FC1)
    gemm_bt<4,64><<<dim3(16, 16, 4), 256, 0, stream>>>(hbuf, fc2_wb, nullptr, nullptr,
                                                       part0, pext, 2048, 1024, 4096, 1024);
    reduce_bias_res<4><<<2048, 256, 0, stream>>>(part0, pext, fc2_b, attn_o, out,
                                                 2048*1024/4, 256);
}

// Round 6
// 166.788 us; speedup vs baseline: 1.7452x; 1.0651x over previous
//
#include <hip/hip_runtime.h>
#include <hip/hip_bf16.h>

typedef unsigned short u16;
typedef __attribute__((ext_vector_type(8))) short bf16x8;
typedef __attribute__((ext_vector_type(4))) float f32x4;

typedef __attribute__((address_space(1))) const void cgvoid;
typedef __attribute__((address_space(3))) void lvoid;

static __device__ __forceinline__ u16 f2bf(float x) {
    __hip_bfloat16 h = __float2bfloat16(x);
    return __builtin_bit_cast(u16, h);
}

static __device__ __forceinline__ void gload_lds16(const u16* g, u16* l) {
    __builtin_amdgcn_global_load_lds((cgvoid*)g, (lvoid*)l, 16, 0, 0);
}

// ---------------------------------------------------------------------------
// prep: blocks [0,2048) = LayerNorm1 rows; blocks [2048,6144) = grid-stride
// f32->bf16 convert of all four weight matrices (segment table, compile-time).
// ---------------------------------------------------------------------------
__global__ __launch_bounds__(256) void prep(
    const float* __restrict__ hidden, const float* __restrict__ g1,
    const float* __restrict__ b1, u16* __restrict__ ln_out,
    const float* __restrict__ qkv_w, const float* __restrict__ dense_w,
    const float* __restrict__ fc1_w, const float* __restrict__ fc2_w,
    u16* __restrict__ qkv_wb, u16* __restrict__ dense_wb,
    u16* __restrict__ fc1_wb, u16* __restrict__ fc2_wb)
{
    const int t = threadIdx.x;
    if (blockIdx.x < 2048) {
        const int row = blockIdx.x;
        const float4 v = ((const float4*)(hidden + (size_t)row * 1024))[t];
        float s  = v.x + v.y + v.z + v.w;
        float sq = v.x*v.x + v.y*v.y + v.z*v.z + v.w*v.w;
#pragma unroll
        for (int d = 1; d < 64; d <<= 1) {
            s  += __shfl_xor(s, d, 64);
            sq += __shfl_xor(sq, d, 64);
        }
        __shared__ float ss[4], ssq[4];
        const int wave = t >> 6, lane = t & 63;
        if (lane == 0) { ss[wave] = s; ssq[wave] = sq; }
        __syncthreads();
        s  = ss[0] + ss[1] + ss[2] + ss[3];
        sq = ssq[0] + ssq[1] + ssq[2] + ssq[3];
        const float mu = s * (1.f / 1024.f);
        const float rinv = rsqrtf(sq * (1.f / 1024.f) - mu * mu + 1e-5f);
        const float4 gv = ((const float4*)g1)[t];
        const float4 bv = ((const float4*)b1)[t];
        ushort4 pk;
        pk.x = f2bf((v.x - mu) * rinv * gv.x + bv.x);
        pk.y = f2bf((v.y - mu) * rinv * gv.y + bv.y);
        pk.z = f2bf((v.z - mu) * rinv * gv.z + bv.z);
        pk.w = f2bf((v.w - mu) * rinv * gv.w + bv.w);
        ((ushort4*)(ln_out + (size_t)row * 1024))[t] = pk;
        return;
    }
    // weight converts: 3,145,728 float4 total
    constexpr int C0 = 786432;            // qkv   3072*1024/4
    constexpr int C1 = C0 + 262144;       // dense 1024*1024/4
    constexpr int C2 = C1 + 1048576;      // fc1   4096*1024/4
    constexpr int C3 = C2 + 1048576;      // fc2   1024*4096/4
    int i = (blockIdx.x - 2048) * 256 + t;
    const int stride = (gridDim.x - 2048) * 256;
    for (; i < C3; i += stride) {
        const float* src; u16* dst; int j;
        if (i < C0)      { src = qkv_w;   dst = qkv_wb;   j = i; }
        else if (i < C1) { src = dense_w; dst = dense_wb; j = i - C0; }
        else if (i < C2) { src = fc1_w;   dst = fc1_wb;   j = i - C1; }
        else             { src = fc2_w;   dst = fc2_wb;   j = i - C2; }
        const float4 v = ((const float4*)src)[j];
        ushort4 pk;
        pk.x = f2bf(v.x); pk.y = f2bf(v.y); pk.z = f2bf(v.z); pk.w = f2bf(v.w);
        ((ushort4*)dst)[j] = pk;
    }
}

// ---------------------------------------------------------------------------
// C[M][N] = A[M][K] @ W[N][K]^T (+ bias + epilogue)
// BM=128, BN=64, BK=64, 4 waves. blockIdx.z = K-split slice (Kspan each).
// EPI: 0 = bf16 out (+bias), 2 = bf16 out + bias + bloom-gelu,
//      4 = raw f32 partial (NO bias) to p0 (z==0) / pext[z-1]
// ---------------------------------------------------------------------------
template<int EPI, int BN>
__global__ __launch_bounds__(256, 4) void gemm_bt(
    const u16* __restrict__ A, const u16* __restrict__ Bw,
    const float* __restrict__ bias, void* __restrict__ Cout,
    float* __restrict__ p0, float* __restrict__ pext,
    int M, int N, int K, int Kspan)
{
    constexpr int WC = BN / 64;
    constexpr int MI = (BN == 128) ? 4 : 2;
    constexpr int NI = 4;
    __shared__ __align__(16) u16 As[128 * 64];
    __shared__ __align__(16) u16 Bs[BN * 64];
    const int t = threadIdx.x;
    const int lane = t & 63;
    const int wave = t >> 6;
    const int wr = wave / WC, wc = wave % WC;
    const int g = lane >> 4, r16 = lane & 15;
    const int tile_m = blockIdx.x * 128;
    const int tile_n = blockIdx.y * BN;
    const int kb = blockIdx.z * Kspan;

    f32x4 acc[MI][NI] = {};

    for (int k0 = kb; k0 < kb + Kspan; k0 += 64) {
        __syncthreads();
#pragma unroll
        for (int i = 0; i < 4; ++i) {
            const int off = (t + i * 256) * 8;
            const int row = off >> 6;
            const int col = off & 63;
            gload_lds16(A + (size_t)(tile_m + row) * K + k0 + col, As + off);
        }
#pragma unroll
        for (int i = 0; i < BN / 32; ++i) {
            const int off = (t + i * 256) * 8;
            const int row = off >> 6;
            const int col = off & 63;
            gload_lds16(Bw + (size_t)(tile_n + row) * K + k0 + col, Bs + off);
        }
        __syncthreads();

        bf16x8 af[MI][2], bfr[NI][2];
#pragma unroll
        for (int mi = 0; mi < MI; ++mi)
#pragma unroll
            for (int ks = 0; ks < 2; ++ks)
                af[mi][ks] = *(const bf16x8*)(As + (wr*(MI*16) + mi*16 + r16)*64 + ks*32 + g*8);
#pragma unroll
        for (int ni = 0; ni < NI; ++ni)
#pragma unroll
            for (int ks = 0; ks < 2; ++ks)
                bfr[ni][ks] = *(const bf16x8*)(Bs + (wc*64 + ni*16 + r16)*64 + ks*32 + g*8);
#pragma unroll
        for (int mi = 0; mi < MI; ++mi)
#pragma unroll
            for (int ni = 0; ni < NI; ++ni) {
                acc[mi][ni] = __builtin_amdgcn_mfma_f32_16x16x32_bf16(af[mi][0], bfr[ni][0], acc[mi][ni], 0, 0, 0);
                acc[mi][ni] = __builtin_amdgcn_mfma_f32_16x16x32_bf16(af[mi][1], bfr[ni][1], acc[mi][ni], 0, 0, 0);
            }
    }

    float* dst = nullptr;
    if constexpr (EPI == 4)
        dst = (blockIdx.z == 0) ? p0 : pext + (size_t)(blockIdx.z - 1) * ((size_t)M * N);

#pragma unroll
    for (int mi = 0; mi < MI; ++mi) {
#pragma unroll
        for (int ni = 0; ni < NI; ++ni) {
            const int col = tile_n + wc*64 + ni*16 + r16;
            const int row0 = tile_m + wr*(MI*16) + mi*16 + g*4;
#pragma unroll
            for (int r = 0; r < 4; ++r) {
                const int row = row0 + r;
                if constexpr (EPI == 4) {
                    dst[(size_t)row * N + col] = acc[mi][ni][r];
                } else if constexpr (EPI == 0) {
                    ((u16*)Cout)[(size_t)row * N + col] = f2bf(acc[mi][ni][r] + bias[col]);
                } else {
                    const float v = acc[mi][ni][r] + bias[col];
                    const float c = 0.79788456f * v * (1.0f + 0.044715f * v * v);
                    ((u16*)Cout)[(size_t)row * N + col] = f2bf(v / (1.0f + __expf(-2.0f * c)));
                }
            }
        }
    }
}

// ---------------------------------------------------------------------------
// dense epilogue: attn_o = p0 + p1 + bias + res; ln_out = LayerNorm(attn_o).
// One block per row (H=1024), 256 threads, float4 per thread.
// ---------------------------------------------------------------------------
__global__ __launch_bounds__(256) void reduce2_ln(
    const float* __restrict__ p0, const float* __restrict__ p1,
    const float* __restrict__ bias, const float* __restrict__ res,
    float* __restrict__ attn_o, const float* __restrict__ g2,
    const float* __restrict__ b2, u16* __restrict__ ln_out)
{
    const int row = blockIdx.x;
    const int t = threadIdx.x;
    const size_t i = (size_t)row * 256 + t;
    const float4 a0 = ((const float4*)p0)[i];
    const float4 a1 = ((const float4*)p1)[i];
    const float4 bv = ((const float4*)bias)[t];
    const float4 rv = ((const float4*)res)[i];
    float4 v;
    v.x = a0.x + a1.x + bv.x + rv.x;
    v.y = a0.y + a1.y + bv.y + rv.y;
    v.z = a0.z + a1.z + bv.z + rv.z;
    v.w = a0.w + a1.w + bv.w + rv.w;
    ((float4*)attn_o)[i] = v;

    float s  = v.x + v.y + v.z + v.w;
    float sq = v.x*v.x + v.y*v.y + v.z*v.z + v.w*v.w;
#pragma unroll
    for (int d = 1; d < 64; d <<= 1) {
        s  += __shfl_xor(s, d, 64);
        sq += __shfl_xor(sq, d, 64);
    }
    __shared__ float ss[4], ssq[4];
    const int wave = t >> 6, lane = t & 63;
    if (lane == 0) { ss[wave] = s; ssq[wave] = sq; }
    __syncthreads();
    s  = ss[0] + ss[1] + ss[2] + ss[3];
    sq = ssq[0] + ssq[1] + ssq[2] + ssq[3];
    const float mu = s * (1.f / 1024.f);
    const float rinv = rsqrtf(sq * (1.f / 1024.f) - mu * mu + 1e-5f);
    const float4 gv = ((const float4*)g2)[t];
    const float4 b2v = ((const float4*)b2)[t];
    ushort4 pk;
    pk.x = f2bf((v.x - mu) * rinv * gv.x + b2v.x);
    pk.y = f2bf((v.y - mu) * rinv * gv.y + b2v.y);
    pk.z = f2bf((v.z - mu) * rinv * gv.z + b2v.z);
    pk.w = f2bf((v.w - mu) * rinv * gv.w + b2v.w);
    ((ushort4*)(ln_out + (size_t)row * 1024))[t] = pk;
}

// ---------------------------------------------------------------------------
// out = p0 + sum(pext[j]) + bias + res   (f32, vectorized)
// ---------------------------------------------------------------------------
template<int NP>
__global__ __launch_bounds__(256) void reduce_bias_res(
    const float* __restrict__ p0, const float* __restrict__ pext,
    const float* __restrict__ bias, const float* __restrict__ res,
    float* __restrict__ out, int n4, int n4row)
{
    int i = blockIdx.x * blockDim.x + threadIdx.x;
    const int stride = gridDim.x * blockDim.x;
    for (; i < n4; i += stride) {
        float4 a = ((const float4*)p0)[i];
#pragma unroll
        for (int j = 0; j < NP - 1; ++j) {
            const float4 b = ((const float4*)pext)[(size_t)j * n4 + i];
            a.x += b.x; a.y += b.y; a.z += b.z; a.w += b.w;
        }
        const float4 bv = ((const float4*)bias)[i & (n4row - 1)];
        const float4 rv = ((const float4*)res)[i];
        float4 o;
        o.x = a.x + bv.x + rv.x;
        o.y = a.y + bv.y + rv.y;
        o.z = a.z + bv.z + rv.z;
        o.w = a.w + bv.w + rv.w;
        ((float4*)out)[i] = o;
    }
}

// ---------------------------------------------------------------------------
// Pack K and V into MFMA-fragment order (gather once, reuse ~64x).
// kP/vP layout: [h][kt][gi=0..7][lane=0..63][e=0..7] (u16), 8KB per (h,kt).
// ---------------------------------------------------------------------------
__global__ __launch_bounds__(256) void pack_kv(
    const u16* __restrict__ fused, u16* __restrict__ kP, u16* __restrict__ vP)
{
    const int bid = blockIdx.x;
    const int h = bid >> 5, kt = bid & 31;
    const int kt0 = kt * 64;
    const int t = threadIdx.x;
    const int lane = t & 63;
    const int g = lane >> 4, r16 = lane & 15;
    const size_t tbase = ((size_t)(h * 32 + kt)) * 4096;

#pragma unroll
    for (int half = 0; half < 2; ++half) {
        const int gi = (t >> 6) + half * 4;          // 0..7
        const int kn = gi >> 1, ks = gi & 1;
        const int w = 32*(kn>>1) + 8*(r16>>2) + 4*(kn&1) + (r16&3);
        const bf16x8 kv = *(const bf16x8*)(fused + (size_t)(kt0 + w) * 3072 + h*192 + 64 + ks*32 + g*8);
        *(bf16x8*)(kP + tbase + gi*512 + lane*8) = kv;
        union { bf16x8 v; u16 e[8]; } uv;
        const u16* vs = fused + (size_t)(kt0 + ks*32 + g*8) * 3072 + h*192 + 128 + kn*16 + r16;
#pragma unroll
        for (int e = 0; e < 8; ++e) uv.e[e] = vs[(size_t)e * 3072];
        *(bf16x8*)(vP + tbase + gi*512 + lane*8) = uv.v;
    }
}

// ---------------------------------------------------------------------------
// Swapped-operand flash attention, 4-way K-split, fragment-packed K/V.
// ---------------------------------------------------------------------------
__global__ __launch_bounds__(256, 4) void attn_swapped(
    const u16* __restrict__ fused, const u16* __restrict__ kP,
    const u16* __restrict__ vP, const float* __restrict__ alibi,
    u16* __restrict__ ctx)
{
    const int bid = blockIdx.x;
    const int h = bid & 15;
    const int qt = 127 - (bid >> 4);        // heavy q-tiles dispatch first
    const int qw0 = qt * 16;
    const int t = threadIdx.x;
    const int lane = t & 63, wave = t >> 6;
    const int g = lane >> 4, r16 = lane & 15;
    const int qrow = qw0 + r16;

    __shared__ float Ms[4][16], Ls[4][16];
    __shared__ float Os[4][4][16][17];      // [wave][nd][d16][q] padded

    const u16* qbase = fused + (size_t)qrow * 3072 + h * 192;
    bf16x8 qf[2];
    qf[0] = *(const bf16x8*)(qbase + g*8);
    qf[1] = *(const bf16x8*)(qbase + 32 + g*8);

    f32x4 o_acc[4] = {};
    float m_r = -3.0e38f, l_r = 0.f;

    const u16* kPh = kP + (size_t)h * 32 * 4096;
    const u16* vPh = vP + (size_t)h * 32 * 4096;
    const float* abase = alibi + (size_t)h * 2048;

    const int nkt = (qw0 >> 6) + 1;
    for (int kt = wave; kt < nkt; kt += 4) {
        const int kt0 = kt * 64;
        const u16* kT = kPh + (size_t)kt * 4096;
        const u16* vT = vPh + (size_t)kt * 4096;

        bf16x8 kf[4][2], vf[4][2];
#pragma unroll
        for (int kn = 0; kn < 4; ++kn) {
            kf[kn][0] = *(const bf16x8*)(kT + (kn*2 + 0)*512 + lane*8);
            kf[kn][1] = *(const bf16x8*)(kT + (kn*2 + 1)*512 + lane*8);
        }
        float4 al[4];
#pragma unroll
        for (int kn = 0; kn < 4; ++kn)
            al[kn] = *(const float4*)(abase + kt0 + 32*(kn>>1) + 8*g + 4*(kn&1));
#pragma unroll
        for (int nd = 0; nd < 4; ++nd) {
            vf[nd][0] = *(const bf16x8*)(vT + (nd*2 + 0)*512 + lane*8);
            vf[nd][1] = *(const bf16x8*)(vT + (nd*2 + 1)*512 + lane*8);
        }

        f32x4 sc[4] = {};
#pragma unroll
        for (int kn = 0; kn < 4; ++kn) {
            sc[kn] = __builtin_amdgcn_mfma_f32_16x16x32_bf16(kf[kn][0], qf[0], sc[kn], 0, 0, 0);
            sc[kn] = __builtin_amdgcn_mfma_f32_16x16x32_bf16(kf[kn][1], qf[1], sc[kn], 0, 0, 0);
        }

        float s[4][4];
        float rmax = -3.0e38f;
#pragma unroll
        for (int kn = 0; kn < 4; ++kn) {
            const int kb = kt0 + 32*(kn>>1) + 8*g + 4*(kn&1);
            const float alv[4] = {al[kn].x, al[kn].y, al[kn].z, al[kn].w};
#pragma unroll
            for (int r = 0; r < 4; ++r) {
                float v = sc[kn][r] * 0.125f + alv[r];
                v = (kb + r <= qrow) ? v : -1.0e30f;
                s[kn][r] = v;
                rmax = fmaxf(rmax, v);
            }
        }
        rmax = fmaxf(rmax, __shfl_xor(rmax, 16, 64));
        rmax = fmaxf(rmax, __shfl_xor(rmax, 32, 64));

        const float mnew = fmaxf(m_r, rmax);
        const float scale = __expf(m_r - mnew);
        m_r = mnew;

        float psum = 0.f;
        u16 ph[4][4];
#pragma unroll
        for (int kn = 0; kn < 4; ++kn)
#pragma unroll
            for (int r = 0; r < 4; ++r) {
                const float p = __expf(s[kn][r] - mnew);
                psum += p;
                ph[kn][r] = f2bf(p);
            }
        psum += __shfl_xor(psum, 16, 64);
        psum += __shfl_xor(psum, 32, 64);
        l_r = l_r * scale + psum;

#pragma unroll
        for (int nd = 0; nd < 4; ++nd)
#pragma unroll
            for (int r = 0; r < 4; ++r)
                o_acc[nd][r] *= scale;

        bf16x8 pf[2];
#pragma unroll
        for (int ks = 0; ks < 2; ++ks) {
            union { bf16x8 v; u16 e[8]; } u;
#pragma unroll
            for (int r = 0; r < 4; ++r) { u.e[r] = ph[2*ks][r]; u.e[4+r] = ph[2*ks+1][r]; }
            pf[ks] = u.v;
        }
#pragma unroll
        for (int nd = 0; nd < 4; ++nd) {
            o_acc[nd] = __builtin_amdgcn_mfma_f32_16x16x32_bf16(vf[nd][0], pf[0], o_acc[nd], 0, 0, 0);
            o_acc[nd] = __builtin_amdgcn_mfma_f32_16x16x32_bf16(vf[nd][1], pf[1], o_acc[nd], 0, 0, 0);
        }
    }

    // -------- merge 4 per-wave partials --------
#pragma unroll
    for (int nd = 0; nd < 4; ++nd)
#pragma unroll
        for (int r = 0; r < 4; ++r)
            Os[wave][nd][g*4 + r][r16] = o_acc[nd][r];
    if (g == 0) { Ms[wave][r16] = m_r; Ls[wave][r16] = l_r; }
    __syncthreads();

    if (wave == 0) {
        const float m0 = Ms[0][r16], m1 = Ms[1][r16], m2 = Ms[2][r16], m3 = Ms[3][r16];
        const float ms = fmaxf(fmaxf(m0, m1), fmaxf(m2, m3));
        const float f0 = __expf(m0 - ms), f1 = __expf(m1 - ms);
        const float f2 = __expf(m2 - ms), f3 = __expf(m3 - ms);
        const float l = f0*Ls[0][r16] + f1*Ls[1][r16] + f2*Ls[2][r16] + f3*Ls[3][r16];
        const float inv = 1.0f / l;
#pragma unroll
        for (int nd = 0; nd < 4; ++nd) {
            float v[4];
#pragma unroll
            for (int r = 0; r < 4; ++r) {
                const int d = g*4 + r;
                v[r] = (f0*Os[0][nd][d][r16] + f1*Os[1][nd][d][r16] +
                        f2*Os[2][nd][d][r16] + f3*Os[3][nd][d][r16]) * inv;
            }
            ushort4 pk;
            pk.x = f2bf(v[0]); pk.y = f2bf(v[1]); pk.z = f2bf(v[2]); pk.w = f2bf(v[3]);
            *(ushort4*)(ctx + (size_t)qrow * 1024 + h*64 + nd*16 + g*4) = pk;
        }
    }
}

// ---------------------------------------------------------------------------
extern "C" void kernel_launch(void* const* d_in, const int* in_sizes, int n_in,
                              void* d_out, int out_size, void* d_ws, size_t ws_size,
                              hipStream_t stream)
{
    (void)in_sizes; (void)n_in; (void)out_size; (void)ws_size;
    const float* hidden  = (const float*)d_in[0];
    const float* alibi   = (const float*)d_in[2];
    const float* ln1_g   = (const float*)d_in[3];
    const float* ln1_b   = (const float*)d_in[4];
    const float* qkv_w   = (const float*)d_in[5];
    const float* qkv_b   = (const float*)d_in[6];
    const float* dense_w = (const float*)d_in[7];
    const float* dense_b = (const float*)d_in[8];
    const float* ln2_g   = (const float*)d_in[9];
    const float* ln2_b   = (const float*)d_in[10];
    const float* fc1_w   = (const float*)d_in[11];
    const float* fc1_b   = (const float*)d_in[12];
    const float* fc2_w   = (const float*)d_in[13];
    const float* fc2_b   = (const float*)d_in[14];
    float* out = (float*)d_out;

    char* p = (char*)d_ws;
    u16* ln_buf   = (u16*)p;  p += (size_t)2048 * 1024 * 2;   // [0,4MB)
    u16* qkv_wb   = (u16*)p;  p += (size_t)3072 * 1024 * 2;   // [4,10)
    u16* fusedq   = (u16*)p;  p += (size_t)2048 * 3072 * 2;   // [10,22)
    u16* ctx      = (u16*)p;  p += (size_t)2048 * 1024 * 2;   // [22,26)
    u16* dense_wb = (u16*)p;  p += (size_t)1024 * 1024 * 2;   // [26,28)
    float* attn_o = (float*)p; p += (size_t)2048 * 1024 * 4;  // [28,36)
    u16* fc1_wb   = (u16*)p;  p += (size_t)4096 * 1024 * 2;   // [36,44)
    u16* fc2_wb   = (u16*)p;  p += (size_t)1024 * 4096 * 2;   // [44,52)
    float* pext   = (float*)p; p += (size_t)3 * 2048 * 1024 * 4; // [52,76) split-K slices 1..3
    float* part0  = (float*)p; p += (size_t)2048 * 1024 * 4;  // [76,84) split-K slice 0
    u16* hbuf = fusedq;            // FC1 out (16MB) aliases fusedq+ctx (dead)
    u16* kP = (u16*)attn_o;        // 4MB, dead before reduce2_ln writes attn_o
    u16* vP = kP + (size_t)16 * 32 * 4096;    // 4MB

    // LN1 + all weight converts, one dispatch
    prep<<<6144, 256, 0, stream>>>(hidden, ln1_g, ln1_b, ln_buf,
                                   qkv_w, dense_w, fc1_w, fc2_w,
                                   qkv_wb, dense_wb, fc1_wb, fc2_wb);
    // QKV: 128x64 tiles, 768 blocks
    gemm_bt<0,64><<<dim3(16, 48), 256, 0, stream>>>(ln_buf, qkv_wb, qkv_b, fusedq,
                                                    nullptr, nullptr, 2048, 3072, 1024, 1024);
    pack_kv<<<512, 256, 0, stream>>>(fusedq, kP, vP);
    attn_swapped<<<2048, 256, 0, stream>>>(fusedq, kP, vP, alibi, ctx);
    // dense: split-K=2, partials -> part0/pext[0]
    gemm_bt<4,64><<<dim3(16, 16, 2), 256, 0, stream>>>(ctx, dense_wb, nullptr, nullptr,
                                                       part0, pext, 2048, 1024, 1024, 512);
    // fused: attn_o = partials+bias+residual; ln_buf = LN2(attn_o)
    reduce2_ln<<<2048, 256, 0, stream>>>(part0, pext, dense_b, hidden, attn_o,
                                         ln2_g, ln2_b, ln_buf);
    // FC1 + gelu: 1024 blocks
    gemm_bt<2,64><<<dim3(16, 64), 256, 0, stream>>>(ln_buf, fc1_wb, fc1_b, hbuf,
                                                    nullptr, nullptr, 2048, 4096, 1024, 1024);
    // FC2: split-K=4
    gemm_bt<4,64><<<dim3(16, 16, 4), 256, 0, stream>>>(hbuf, fc2_wb, nullptr, nullptr,
                                                       part0, pext, 2048, 1024, 4096, 1024);
    reduce_bias_res<4><<<2048, 256, 0, stream>>>(part0, pext, fc2_b, attn_o, out,
                                                 2048*1024/4, 256);
}